// Round 3
// baseline (747.927 us; speedup 1.0000x reference)
//
#include <hip/hip_runtime.h>

// Problem constants: N=50000, E=1.6M, dims 512 -> 128 -> 64
#define IN_DIM  512
#define HID_DIM 128
#define OUT_DIM 64

// ---------------------------------------------------------------------------
// CSR build: degree histogram -> single-block scan -> scatter (packed records)
// ---------------------------------------------------------------------------

__global__ void k_zero(int* __restrict__ p, int n) {
    int i = blockIdx.x * blockDim.x + threadIdx.x;
    if (i < n) p[i] = 0;
}

__global__ void k_hist(const int* __restrict__ rows, int* __restrict__ deg, int E) {
    int i = blockIdx.x * blockDim.x + threadIdx.x;
    if (i < E) atomicAdd(&deg[rows[i]], 1);
}

__global__ __launch_bounds__(1024) void k_scan(const int* __restrict__ deg,
                                               int* __restrict__ row_ptr,
                                               int* __restrict__ row_fill,
                                               int n, int E) {
    __shared__ int s[1024];
    const int tid = threadIdx.x;
    const int CH = (n + 1023) >> 10;
    const int base = tid * CH;

    int sum = 0;
    for (int i = 0; i < CH; ++i) {
        int idx = base + i;
        if (idx < n) sum += deg[idx];
    }
    s[tid] = sum;
    __syncthreads();
    for (int off = 1; off < 1024; off <<= 1) {
        int v = (tid >= off) ? s[tid - off] : 0;
        __syncthreads();
        s[tid] += v;
        __syncthreads();
    }
    int running = (tid == 0) ? 0 : s[tid - 1];
    for (int i = 0; i < CH; ++i) {
        int idx = base + i;
        if (idx < n) {
            row_ptr[idx]  = running;
            row_fill[idx] = running;
            running += deg[idx];
        }
    }
    if (tid == 0) row_ptr[n] = E;
}

// Packed edge record: .x = col, .y = float bits of weight. One 8B store.
__global__ void k_scatter(const int* __restrict__ rows, const int* __restrict__ cols,
                          const float* __restrict__ ew, int* __restrict__ row_fill,
                          int2* __restrict__ ep, int E) {
    int i = blockIdx.x * blockDim.x + threadIdx.x;
    if (i < E) {
        int r = rows[i];
        int p = atomicAdd(&row_fill[r], 1);
        ep[p] = make_int2(cols[i], __float_as_int(ew[i]));
    }
}

// ---------------------------------------------------------------------------
// Split-K tiled GEMM: P[ks][n x DC] partial = A[:, ks-chunk] @ W[ks-chunk, :]
// Block: 256 threads, 128-row x DC-col tile, BK=16, microtile TM x TN.
// blockIdx.y = K-split index; KCHUNK = K handled per block.
// ---------------------------------------------------------------------------
template <int DK, int DC, int TN, int KCHUNK>
__global__ __launch_bounds__(256) void k_gemm(const float* __restrict__ A,
                                              const float* __restrict__ W,
                                              float* __restrict__ P, int n) {
    constexpr int BR = 128, BK = 16, TM = 8;
    constexpr int TX = DC / TN;          // 16 in both instantiations
    static_assert(TX * (BR / TM) == 256, "thread layout");

    __shared__ float As[BK][BR];         // A tile, transposed
    __shared__ float Ws[BK][DC];         // W tile, row-major

    const int tid  = threadIdx.x;
    const int tx   = tid % TX;
    const int ty   = tid / TX;
    const int row0 = blockIdx.x * BR;
    const int kbeg = blockIdx.y * KCHUNK;
    float* __restrict__ Pp = P + (size_t)blockIdx.y * n * DC;

    float acc[TM][TN];
#pragma unroll
    for (int i = 0; i < TM; ++i)
#pragma unroll
        for (int j = 0; j < TN; ++j) acc[i][j] = 0.f;

    for (int k0 = kbeg; k0 < kbeg + KCHUNK; k0 += BK) {
        __syncthreads();

        // stage A: 128 rows x 16 k = 512 float4, 2 per thread (transposed)
#pragma unroll
        for (int l = 0; l < 2; ++l) {
            int q   = tid + l * 256;
            int row = q & 127;
            int kq  = q >> 7;            // 0..3
            int rr  = row0 + row;
            if (rr >= n) rr = n - 1;     // clamp; dup discarded at store
            float4 v = *reinterpret_cast<const float4*>(&A[(size_t)rr * DK + k0 + 4 * kq]);
            As[4 * kq + 0][row] = v.x;
            As[4 * kq + 1][row] = v.y;
            As[4 * kq + 2][row] = v.z;
            As[4 * kq + 3][row] = v.w;
        }
        // stage W: 16 x DC, coalesced float4
        constexpr int WL = (BK * DC / 4) / 256;  // 2 for DC=128, 1 for DC=64
#pragma unroll
        for (int l = 0; l < WL; ++l) {
            int q = tid + l * 256;
            int k = (q * 4) / DC;
            int c = (q * 4) % DC;
            *reinterpret_cast<float4*>(&Ws[k][c]) =
                *reinterpret_cast<const float4*>(&W[(size_t)(k0 + k) * DC + c]);
        }
        __syncthreads();

#pragma unroll
        for (int k = 0; k < BK; ++k) {
            float a[TM], w[TN];
#pragma unroll
            for (int i = 0; i < TM; i += 4) {
                float4 v = *reinterpret_cast<const float4*>(&As[k][ty * TM + i]);
                a[i] = v.x; a[i + 1] = v.y; a[i + 2] = v.z; a[i + 3] = v.w;
            }
#pragma unroll
            for (int j = 0; j < TN; j += 4) {
                float4 v = *reinterpret_cast<const float4*>(&Ws[k][tx * TN + j]);
                w[j] = v.x; w[j + 1] = v.y; w[j + 2] = v.z; w[j + 3] = v.w;
            }
#pragma unroll
            for (int i = 0; i < TM; ++i)
#pragma unroll
                for (int j = 0; j < TN; ++j)
                    acc[i][j] = fmaf(a[i], w[j], acc[i][j]);
        }
    }

#pragma unroll
    for (int i = 0; i < TM; ++i) {
        int r = row0 + ty * TM + i;
        if (r < n) {
#pragma unroll
            for (int j = 0; j < TN; j += 4) {
                float4 v = make_float4(acc[i][j], acc[i][j + 1], acc[i][j + 2], acc[i][j + 3]);
                *reinterpret_cast<float4*>(&Pp[(size_t)r * DC + tx * TN + j]) = v;
            }
        }
    }
}

// dst[i] = sum_{s < ks} src[s*len + i], float4-vectorized. len % 4 == 0.
__global__ void k_combine(float* __restrict__ dst, const float* __restrict__ src,
                          size_t len, int ks) {
    size_t i = ((size_t)blockIdx.x * blockDim.x + threadIdx.x) * 4;
    if (i >= len) return;
    float4 a = *reinterpret_cast<const float4*>(&src[i]);
    for (int s = 1; s < ks; ++s) {
        float4 b = *reinterpret_cast<const float4*>(&src[s * len + i]);
        a.x += b.x; a.y += b.y; a.z += b.z; a.w += b.w;
    }
    *reinterpret_cast<float4*>(&dst[i]) = a;
}

// ---------------------------------------------------------------------------
// CSR SpMM, one WAVE per row. Lane covers the feature dim (float2 for D=128,
// float for D=64). Edge records are wave-uniform int2 loads. Unroll 4.
// ---------------------------------------------------------------------------
template <int D, bool RELU>
__global__ __launch_bounds__(256) void k_spmm(const int* __restrict__ rp,
                                              const int2* __restrict__ ep,
                                              const float* __restrict__ sup,
                                              const float* __restrict__ bias,
                                              float* __restrict__ out, int n) {
    const int w    = (blockIdx.x * 256 + threadIdx.x) >> 6;   // wave id = row
    const int lane = threadIdx.x & 63;
    if (w >= n) return;
    const int s = rp[w], e = rp[w + 1];

    if constexpr (D == 128) {
        const int d = lane * 2;
        float2 acc = make_float2(0.f, 0.f);
        int i = s;
        for (; i + 4 <= e; i += 4) {
            int2 r0 = ep[i], r1 = ep[i + 1], r2 = ep[i + 2], r3 = ep[i + 3];
            float2 v0 = *reinterpret_cast<const float2*>(&sup[(size_t)r0.x * D + d]);
            float2 v1 = *reinterpret_cast<const float2*>(&sup[(size_t)r1.x * D + d]);
            float2 v2 = *reinterpret_cast<const float2*>(&sup[(size_t)r2.x * D + d]);
            float2 v3 = *reinterpret_cast<const float2*>(&sup[(size_t)r3.x * D + d]);
            float w0 = __int_as_float(r0.y), w1 = __int_as_float(r1.y);
            float w2 = __int_as_float(r2.y), w3 = __int_as_float(r3.y);
            acc.x = fmaf(w0, v0.x, acc.x); acc.y = fmaf(w0, v0.y, acc.y);
            acc.x = fmaf(w1, v1.x, acc.x); acc.y = fmaf(w1, v1.y, acc.y);
            acc.x = fmaf(w2, v2.x, acc.x); acc.y = fmaf(w2, v2.y, acc.y);
            acc.x = fmaf(w3, v3.x, acc.x); acc.y = fmaf(w3, v3.y, acc.y);
        }
        for (; i < e; ++i) {
            int2 r = ep[i];
            float2 v = *reinterpret_cast<const float2*>(&sup[(size_t)r.x * D + d]);
            float ww = __int_as_float(r.y);
            acc.x = fmaf(ww, v.x, acc.x); acc.y = fmaf(ww, v.y, acc.y);
        }
        float2 b = *reinterpret_cast<const float2*>(&bias[d]);
        acc.x += b.x; acc.y += b.y;
        if (RELU) { acc.x = fmaxf(acc.x, 0.f); acc.y = fmaxf(acc.y, 0.f); }
        *reinterpret_cast<float2*>(&out[(size_t)w * D + d]) = acc;
    } else {
        const int d = lane;
        float acc = 0.f;
        int i = s;
        for (; i + 4 <= e; i += 4) {
            int2 r0 = ep[i], r1 = ep[i + 1], r2 = ep[i + 2], r3 = ep[i + 3];
            float v0 = sup[(size_t)r0.x * D + d];
            float v1 = sup[(size_t)r1.x * D + d];
            float v2 = sup[(size_t)r2.x * D + d];
            float v3 = sup[(size_t)r3.x * D + d];
            acc = fmaf(__int_as_float(r0.y), v0, acc);
            acc = fmaf(__int_as_float(r1.y), v1, acc);
            acc = fmaf(__int_as_float(r2.y), v2, acc);
            acc = fmaf(__int_as_float(r3.y), v3, acc);
        }
        for (; i < e; ++i) {
            int2 r = ep[i];
            acc = fmaf(__int_as_float(r.y), sup[(size_t)r.x * D + d], acc);
        }
        acc += bias[d];
        if (RELU) acc = fmaxf(acc, 0.f);
        out[(size_t)w * D + d] = acc;
    }
}

// ---------------------------------------------------------------------------

extern "C" void kernel_launch(void* const* d_in, const int* in_sizes, int n_in,
                              void* d_out, int out_size, void* d_ws, size_t ws_size,
                              hipStream_t stream) {
    const float* x  = (const float*)d_in[0];
    const int*   ei = (const int*)d_in[1];
    const float* ew = (const float*)d_in[2];
    const float* W1 = (const float*)d_in[3];
    const float* b1 = (const float*)d_in[4];
    const float* W2 = (const float*)d_in[5];
    const float* b2 = (const float*)d_in[6];
    float* out = (float*)d_out;

    const int n = in_sizes[0] / IN_DIM;  // 50000
    const int E = in_sizes[2];           // 1600000
    const int* rows = ei;
    const int* cols = ei + E;

    char* ws = (char*)d_ws;
    size_t off = 0;
    auto alloc = [&](size_t bytes) -> void* {
        off = (off + 255) & ~(size_t)255;
        void* p = ws + off;
        off += bytes;
        return p;
    };
    int2*  ep       = (int2*)alloc((size_t)E * sizeof(int2));
    int*   deg      = (int*)alloc((size_t)n * sizeof(int));
    int*   row_ptr  = (int*)alloc((size_t)(n + 1) * sizeof(int));
    int*   row_fill = (int*)alloc((size_t)n * sizeof(int));
    float* sup1     = (float*)alloc((size_t)n * HID_DIM * sizeof(float));
    float* h        = (float*)alloc((size_t)n * HID_DIM * sizeof(float));
    float* sup2     = sup1;  // sup1 dead after spmm1

    // Partial-sum region for split-K (reused by both GEMMs). Choose the
    // largest KS1 in {4,2,1} that fits ws_size; KS1==1 => write sup1 direct.
    size_t fixed = (off + 255) & ~(size_t)255;
    size_t per_split1 = (size_t)n * HID_DIM * sizeof(float);   // 25.6 MB
    size_t per_split2 = (size_t)n * OUT_DIM * sizeof(float);   // 12.8 MB
    int KS1 = 1;
    if (fixed + 4 * per_split1 <= ws_size) KS1 = 4;
    else if (fixed + 2 * per_split1 <= ws_size) KS1 = 2;
    size_t pbytes = (KS1 > 1) ? KS1 * per_split1 : 0;
    if (pbytes < 2 * per_split2 && fixed + 2 * per_split2 <= ws_size)
        pbytes = 2 * per_split2;
    float* pbuf = (float*)alloc(pbytes);   // may be zero-sized
    int KS2 = (pbytes >= 2 * per_split2) ? 2 : 1;

    float* p1 = (KS1 > 1) ? pbuf : sup1;
    float* p2 = (KS2 > 1) ? pbuf : sup2;

    const int gemm_rb = (n + 127) / 128;  // 391

    // --- CSR build ---
    k_zero<<<(n + 255) / 256, 256, 0, stream>>>(deg, n);
    k_hist<<<(E + 255) / 256, 256, 0, stream>>>(rows, deg, E);
    k_scan<<<1, 1024, 0, stream>>>(deg, row_ptr, row_fill, n, E);
    k_scatter<<<(E + 255) / 256, 256, 0, stream>>>(rows, cols, ew, row_fill, ep, E);

    // --- Layer 1: GEMM (split-K) + combine + SpMM ---
    {
        dim3 g(gemm_rb, KS1);
        if (KS1 == 4)
            k_gemm<IN_DIM, HID_DIM, 8, IN_DIM / 4><<<g, 256, 0, stream>>>(x, W1, p1, n);
        else if (KS1 == 2)
            k_gemm<IN_DIM, HID_DIM, 8, IN_DIM / 2><<<g, 256, 0, stream>>>(x, W1, p1, n);
        else
            k_gemm<IN_DIM, HID_DIM, 8, IN_DIM><<<g, 256, 0, stream>>>(x, W1, p1, n);
        if (KS1 > 1) {
            size_t len = (size_t)n * HID_DIM;
            k_combine<<<(int)((len / 4 + 255) / 256), 256, 0, stream>>>(sup1, p1, len, KS1);
        }
    }
    k_spmm<HID_DIM, true><<<(n + 3) / 4, 256, 0, stream>>>(row_ptr, ep, sup1, b1, h, n);

    // --- Layer 2: GEMM (split-K) + combine + SpMM ---
    {
        dim3 g(gemm_rb, KS2);
        if (KS2 == 2)
            k_gemm<HID_DIM, OUT_DIM, 4, HID_DIM / 2><<<g, 256, 0, stream>>>(h, W2, p2, n);
        else
            k_gemm<HID_DIM, OUT_DIM, 4, HID_DIM><<<g, 256, 0, stream>>>(h, W2, p2, n);
        if (KS2 > 1) {
            size_t len = (size_t)n * OUT_DIM;
            k_combine<<<(int)((len / 4 + 255) / 256), 256, 0, stream>>>(sup2, p2, len, KS2);
        }
    }
    k_spmm<OUT_DIM, false><<<(n + 3) / 4, 256, 0, stream>>>(row_ptr, ep, sup2, b2, out, n);
}

// Round 4
// 630.036 us; speedup vs baseline: 1.1871x; 1.1871x over previous
//
#include <hip/hip_runtime.h>

// Problem constants: N=50000, E=1.6M, dims 512 -> 128 -> 64
#define IN_DIM  512
#define HID_DIM 128
#define OUT_DIM 64

// ---------------------------------------------------------------------------
// CSR build: degree histogram -> 3-kernel reduce-then-scan -> scatter
// ---------------------------------------------------------------------------

__global__ void k_zero(int* __restrict__ p, int n) {
    int i = blockIdx.x * blockDim.x + threadIdx.x;
    if (i < n) p[i] = 0;
}

__global__ void k_hist(const int* __restrict__ rows, int* __restrict__ deg, int E) {
    int i = blockIdx.x * blockDim.x + threadIdx.x;
    if (i < E) atomicAdd(&deg[rows[i]], 1);
}

// Scan tile: 256 threads x 8 ints = 2048 elements per block.
#define SCAN_TILE 2048

// S1: per-block sum of deg tile -> bsum[b]
__global__ __launch_bounds__(256) void k_scan1(const int* __restrict__ deg,
                                               int* __restrict__ bsum, int n) {
    __shared__ int s[256];
    const int tid = threadIdx.x;
    const int base = blockIdx.x * SCAN_TILE + tid * 8;
    int sum = 0;
    if (base + 8 <= n) {
        int4 a = *reinterpret_cast<const int4*>(&deg[base]);
        int4 c = *reinterpret_cast<const int4*>(&deg[base + 4]);
        sum = a.x + a.y + a.z + a.w + c.x + c.y + c.z + c.w;
    } else {
#pragma unroll
        for (int i = 0; i < 8; ++i) { int idx = base + i; if (idx < n) sum += deg[idx]; }
    }
    s[tid] = sum;
    __syncthreads();
#pragma unroll
    for (int off = 128; off > 0; off >>= 1) {
        if (tid < off) s[tid] += s[tid + off];
        __syncthreads();
    }
    if (tid == 0) bsum[blockIdx.x] = s[0];
}

// S2: exclusive scan of nb (<=256) block sums -> bscan
__global__ __launch_bounds__(256) void k_scan2(const int* __restrict__ bsum,
                                               int* __restrict__ bscan, int nb) {
    __shared__ int s[256];
    const int tid = threadIdx.x;
    s[tid] = (tid < nb) ? bsum[tid] : 0;
    __syncthreads();
#pragma unroll
    for (int off = 1; off < 256; off <<= 1) {
        int v = (tid >= off) ? s[tid - off] : 0;
        __syncthreads();
        s[tid] += v;
        __syncthreads();
    }
    if (tid < nb) bscan[tid] = (tid == 0) ? 0 : s[tid - 1];
}

// S3: per-block exclusive scan + block offset -> row_ptr, row_fill
__global__ __launch_bounds__(256) void k_scan3(const int* __restrict__ deg,
                                               const int* __restrict__ bscan,
                                               int* __restrict__ row_ptr,
                                               int* __restrict__ row_fill,
                                               int n, int E) {
    __shared__ int s[256];
    const int tid = threadIdx.x;
    const int base = blockIdx.x * SCAN_TILE + tid * 8;
    int v[8];
    if (base + 8 <= n) {
        int4 a = *reinterpret_cast<const int4*>(&deg[base]);
        int4 c = *reinterpret_cast<const int4*>(&deg[base + 4]);
        v[0] = a.x; v[1] = a.y; v[2] = a.z; v[3] = a.w;
        v[4] = c.x; v[5] = c.y; v[6] = c.z; v[7] = c.w;
    } else {
#pragma unroll
        for (int i = 0; i < 8; ++i) { int idx = base + i; v[i] = (idx < n) ? deg[idx] : 0; }
    }
    int sum = 0;
#pragma unroll
    for (int i = 0; i < 8; ++i) sum += v[i];
    s[tid] = sum;
    __syncthreads();
#pragma unroll
    for (int off = 1; off < 256; off <<= 1) {
        int t = (tid >= off) ? s[tid - off] : 0;
        __syncthreads();
        s[tid] += t;
        __syncthreads();
    }
    int run = bscan[blockIdx.x] + ((tid == 0) ? 0 : s[tid - 1]);
#pragma unroll
    for (int i = 0; i < 8; ++i) {
        int idx = base + i;
        if (idx < n) {
            row_ptr[idx]  = run;
            row_fill[idx] = run;
            run += v[i];
        }
    }
    if (blockIdx.x == 0 && tid == 0) row_ptr[n] = E;
}

// Packed edge record: .x = col, .y = float bits of weight. One 8B store.
__global__ void k_scatter(const int* __restrict__ rows, const int* __restrict__ cols,
                          const float* __restrict__ ew, int* __restrict__ row_fill,
                          int2* __restrict__ ep, int E) {
    int i = blockIdx.x * blockDim.x + threadIdx.x;
    if (i < E) {
        int r = rows[i];
        int p = atomicAdd(&row_fill[r], 1);
        ep[p] = make_int2(cols[i], __float_as_int(ew[i]));
    }
}

// ---------------------------------------------------------------------------
// Split-K tiled GEMM: P[ks][n x DC] partial = A[:, ks-chunk] @ W[ks-chunk, :]
// ---------------------------------------------------------------------------
template <int DK, int DC, int TN, int KCHUNK>
__global__ __launch_bounds__(256) void k_gemm(const float* __restrict__ A,
                                              const float* __restrict__ W,
                                              float* __restrict__ P, int n) {
    constexpr int BR = 128, BK = 16, TM = 8;
    constexpr int TX = DC / TN;
    static_assert(TX * (BR / TM) == 256, "thread layout");

    __shared__ float As[BK][BR];
    __shared__ float Ws[BK][DC];

    const int tid  = threadIdx.x;
    const int tx   = tid % TX;
    const int ty   = tid / TX;
    const int row0 = blockIdx.x * BR;
    const int kbeg = blockIdx.y * KCHUNK;
    float* __restrict__ Pp = P + (size_t)blockIdx.y * n * DC;

    float acc[TM][TN];
#pragma unroll
    for (int i = 0; i < TM; ++i)
#pragma unroll
        for (int j = 0; j < TN; ++j) acc[i][j] = 0.f;

    for (int k0 = kbeg; k0 < kbeg + KCHUNK; k0 += BK) {
        __syncthreads();
#pragma unroll
        for (int l = 0; l < 2; ++l) {
            int q   = tid + l * 256;
            int row = q & 127;
            int kq  = q >> 7;
            int rr  = row0 + row;
            if (rr >= n) rr = n - 1;
            float4 v = *reinterpret_cast<const float4*>(&A[(size_t)rr * DK + k0 + 4 * kq]);
            As[4 * kq + 0][row] = v.x;
            As[4 * kq + 1][row] = v.y;
            As[4 * kq + 2][row] = v.z;
            As[4 * kq + 3][row] = v.w;
        }
        constexpr int WL = (BK * DC / 4) / 256;
#pragma unroll
        for (int l = 0; l < WL; ++l) {
            int q = tid + l * 256;
            int k = (q * 4) / DC;
            int c = (q * 4) % DC;
            *reinterpret_cast<float4*>(&Ws[k][c]) =
                *reinterpret_cast<const float4*>(&W[(size_t)(k0 + k) * DC + c]);
        }
        __syncthreads();

#pragma unroll
        for (int k = 0; k < BK; ++k) {
            float a[TM], w[TN];
#pragma unroll
            for (int i = 0; i < TM; i += 4) {
                float4 v = *reinterpret_cast<const float4*>(&As[k][ty * TM + i]);
                a[i] = v.x; a[i + 1] = v.y; a[i + 2] = v.z; a[i + 3] = v.w;
            }
#pragma unroll
            for (int j = 0; j < TN; j += 4) {
                float4 v = *reinterpret_cast<const float4*>(&Ws[k][tx * TN + j]);
                w[j] = v.x; w[j + 1] = v.y; w[j + 2] = v.z; w[j + 3] = v.w;
            }
#pragma unroll
            for (int i = 0; i < TM; ++i)
#pragma unroll
                for (int j = 0; j < TN; ++j)
                    acc[i][j] = fmaf(a[i], w[j], acc[i][j]);
        }
    }

#pragma unroll
    for (int i = 0; i < TM; ++i) {
        int r = row0 + ty * TM + i;
        if (r < n) {
#pragma unroll
            for (int j = 0; j < TN; j += 4) {
                float4 v = make_float4(acc[i][j], acc[i][j + 1], acc[i][j + 2], acc[i][j + 3]);
                *reinterpret_cast<float4*>(&Pp[(size_t)r * DC + tx * TN + j]) = v;
            }
        }
    }
}

// dst[i] = sum_{s < ks} src[s*len + i], float4-vectorized. len % 4 == 0.
__global__ void k_combine(float* __restrict__ dst, const float* __restrict__ src,
                          size_t len, int ks) {
    size_t i = ((size_t)blockIdx.x * blockDim.x + threadIdx.x) * 4;
    if (i >= len) return;
    float4 a = *reinterpret_cast<const float4*>(&src[i]);
    for (int s = 1; s < ks; ++s) {
        float4 b = *reinterpret_cast<const float4*>(&src[s * len + i]);
        a.x += b.x; a.y += b.y; a.z += b.z; a.w += b.w;
    }
    *reinterpret_cast<float4*>(&dst[i]) = a;
}

// ---------------------------------------------------------------------------
// CSR SpMM, one WAVE per row. Lane covers the feature dim (float2 for D=128,
// float for D=64). Edge records are wave-uniform int2 loads. Unroll 4.
// ---------------------------------------------------------------------------
template <int D, bool RELU>
__global__ __launch_bounds__(256) void k_spmm(const int* __restrict__ rp,
                                              const int2* __restrict__ ep,
                                              const float* __restrict__ sup,
                                              const float* __restrict__ bias,
                                              float* __restrict__ out, int n) {
    const int w    = (blockIdx.x * 256 + threadIdx.x) >> 6;
    const int lane = threadIdx.x & 63;
    if (w >= n) return;
    const int s = rp[w], e = rp[w + 1];

    if constexpr (D == 128) {
        const int d = lane * 2;
        float2 acc = make_float2(0.f, 0.f);
        int i = s;
        for (; i + 4 <= e; i += 4) {
            int2 r0 = ep[i], r1 = ep[i + 1], r2 = ep[i + 2], r3 = ep[i + 3];
            float2 v0 = *reinterpret_cast<const float2*>(&sup[(size_t)r0.x * D + d]);
            float2 v1 = *reinterpret_cast<const float2*>(&sup[(size_t)r1.x * D + d]);
            float2 v2 = *reinterpret_cast<const float2*>(&sup[(size_t)r2.x * D + d]);
            float2 v3 = *reinterpret_cast<const float2*>(&sup[(size_t)r3.x * D + d]);
            float w0 = __int_as_float(r0.y), w1 = __int_as_float(r1.y);
            float w2 = __int_as_float(r2.y), w3 = __int_as_float(r3.y);
            acc.x = fmaf(w0, v0.x, acc.x); acc.y = fmaf(w0, v0.y, acc.y);
            acc.x = fmaf(w1, v1.x, acc.x); acc.y = fmaf(w1, v1.y, acc.y);
            acc.x = fmaf(w2, v2.x, acc.x); acc.y = fmaf(w2, v2.y, acc.y);
            acc.x = fmaf(w3, v3.x, acc.x); acc.y = fmaf(w3, v3.y, acc.y);
        }
        for (; i < e; ++i) {
            int2 r = ep[i];
            float2 v = *reinterpret_cast<const float2*>(&sup[(size_t)r.x * D + d]);
            float ww = __int_as_float(r.y);
            acc.x = fmaf(ww, v.x, acc.x); acc.y = fmaf(ww, v.y, acc.y);
        }
        float2 b = *reinterpret_cast<const float2*>(&bias[d]);
        acc.x += b.x; acc.y += b.y;
        if (RELU) { acc.x = fmaxf(acc.x, 0.f); acc.y = fmaxf(acc.y, 0.f); }
        *reinterpret_cast<float2*>(&out[(size_t)w * D + d]) = acc;
    } else {
        const int d = lane;
        float acc = 0.f;
        int i = s;
        for (; i + 4 <= e; i += 4) {
            int2 r0 = ep[i], r1 = ep[i + 1], r2 = ep[i + 2], r3 = ep[i + 3];
            float v0 = sup[(size_t)r0.x * D + d];
            float v1 = sup[(size_t)r1.x * D + d];
            float v2 = sup[(size_t)r2.x * D + d];
            float v3 = sup[(size_t)r3.x * D + d];
            acc = fmaf(__int_as_float(r0.y), v0, acc);
            acc = fmaf(__int_as_float(r1.y), v1, acc);
            acc = fmaf(__int_as_float(r2.y), v2, acc);
            acc = fmaf(__int_as_float(r3.y), v3, acc);
        }
        for (; i < e; ++i) {
            int2 r = ep[i];
            acc = fmaf(__int_as_float(r.y), sup[(size_t)r.x * D + d], acc);
        }
        acc += bias[d];
        if (RELU) acc = fmaxf(acc, 0.f);
        out[(size_t)w * D + d] = acc;
    }
}

// ---------------------------------------------------------------------------

extern "C" void kernel_launch(void* const* d_in, const int* in_sizes, int n_in,
                              void* d_out, int out_size, void* d_ws, size_t ws_size,
                              hipStream_t stream) {
    const float* x  = (const float*)d_in[0];
    const int*   ei = (const int*)d_in[1];
    const float* ew = (const float*)d_in[2];
    const float* W1 = (const float*)d_in[3];
    const float* b1 = (const float*)d_in[4];
    const float* W2 = (const float*)d_in[5];
    const float* b2 = (const float*)d_in[6];
    float* out = (float*)d_out;

    const int n = in_sizes[0] / IN_DIM;  // 50000
    const int E = in_sizes[2];           // 1600000
    const int* rows = ei;
    const int* cols = ei + E;

    char* ws = (char*)d_ws;
    size_t off = 0;
    auto alloc = [&](size_t bytes) -> void* {
        off = (off + 255) & ~(size_t)255;
        void* p = ws + off;
        off += bytes;
        return p;
    };
    int2*  ep       = (int2*)alloc((size_t)E * sizeof(int2));
    int*   deg      = (int*)alloc((size_t)n * sizeof(int));
    int*   row_ptr  = (int*)alloc((size_t)(n + 1) * sizeof(int));
    int*   row_fill = (int*)alloc((size_t)n * sizeof(int));
    int*   bsum     = (int*)alloc(256 * sizeof(int));
    int*   bscan    = (int*)alloc(256 * sizeof(int));
    float* sup1     = (float*)alloc((size_t)n * HID_DIM * sizeof(float));
    float* h        = (float*)alloc((size_t)n * HID_DIM * sizeof(float));
    float* sup2     = sup1;  // sup1 dead after spmm1

    // Split-K partials region (sized to fit ws)
    size_t fixed = (off + 255) & ~(size_t)255;
    size_t per_split1 = (size_t)n * HID_DIM * sizeof(float);
    size_t per_split2 = (size_t)n * OUT_DIM * sizeof(float);
    int KS1 = 1;
    if (fixed + 4 * per_split1 <= ws_size) KS1 = 4;
    else if (fixed + 2 * per_split1 <= ws_size) KS1 = 2;
    size_t pbytes = (KS1 > 1) ? KS1 * per_split1 : 0;
    if (pbytes < 2 * per_split2 && fixed + 2 * per_split2 <= ws_size)
        pbytes = 2 * per_split2;
    float* pbuf = (float*)alloc(pbytes);
    int KS2 = (pbytes >= 2 * per_split2) ? 2 : 1;

    float* p1 = (KS1 > 1) ? pbuf : sup1;
    float* p2 = (KS2 > 1) ? pbuf : sup2;

    const int gemm_rb = (n + 127) / 128;
    const int nb = (n + SCAN_TILE - 1) / SCAN_TILE;  // 25 (must be <= 256)

    // --- CSR build ---
    k_zero<<<(n + 255) / 256, 256, 0, stream>>>(deg, n);
    k_hist<<<(E + 255) / 256, 256, 0, stream>>>(rows, deg, E);
    k_scan1<<<nb, 256, 0, stream>>>(deg, bsum, n);
    k_scan2<<<1, 256, 0, stream>>>(bsum, bscan, nb);
    k_scan3<<<nb, 256, 0, stream>>>(deg, bscan, row_ptr, row_fill, n, E);
    k_scatter<<<(E + 255) / 256, 256, 0, stream>>>(rows, cols, ew, row_fill, ep, E);

    // --- Layer 1 ---
    {
        dim3 g(gemm_rb, KS1);
        if (KS1 == 4)
            k_gemm<IN_DIM, HID_DIM, 8, IN_DIM / 4><<<g, 256, 0, stream>>>(x, W1, p1, n);
        else if (KS1 == 2)
            k_gemm<IN_DIM, HID_DIM, 8, IN_DIM / 2><<<g, 256, 0, stream>>>(x, W1, p1, n);
        else
            k_gemm<IN_DIM, HID_DIM, 8, IN_DIM><<<g, 256, 0, stream>>>(x, W1, p1, n);
        if (KS1 > 1) {
            size_t len = (size_t)n * HID_DIM;
            k_combine<<<(int)((len / 4 + 255) / 256), 256, 0, stream>>>(sup1, p1, len, KS1);
        }
    }
    k_spmm<HID_DIM, true><<<(n + 3) / 4, 256, 0, stream>>>(row_ptr, ep, sup1, b1, h, n);

    // --- Layer 2 ---
    {
        dim3 g(gemm_rb, KS2);
        if (KS2 == 2)
            k_gemm<HID_DIM, OUT_DIM, 4, HID_DIM / 2><<<g, 256, 0, stream>>>(h, W2, p2, n);
        else
            k_gemm<HID_DIM, OUT_DIM, 4, HID_DIM><<<g, 256, 0, stream>>>(h, W2, p2, n);
        if (KS2 > 1) {
            size_t len = (size_t)n * OUT_DIM;
            k_combine<<<(int)((len / 4 + 255) / 256), 256, 0, stream>>>(sup2, p2, len, KS2);
        }
    }
    k_spmm<OUT_DIM, false><<<(n + 3) / 4, 256, 0, stream>>>(row_ptr, ep, sup2, b2, out, n);
}

// Round 5
// 556.585 us; speedup vs baseline: 1.3438x; 1.1320x over previous
//
#include <hip/hip_runtime.h>

// Problem constants: N=50000, E=1.6M, dims 512 -> 128 -> 64
#define IN_DIM  512
#define HID_DIM 128
#define OUT_DIM 64

// ---------------------------------------------------------------------------
// CSR build: degree histogram -> reduce-then-scan -> binned two-phase scatter
// ---------------------------------------------------------------------------

__global__ void k_zero(int* __restrict__ p, int n) {
    int i = blockIdx.x * blockDim.x + threadIdx.x;
    if (i < n) p[i] = 0;
}

__global__ void k_hist(const int* __restrict__ rows, int* __restrict__ deg, int E) {
    int i = blockIdx.x * blockDim.x + threadIdx.x;
    if (i < E) atomicAdd(&deg[rows[i]], 1);
}

#define SCAN_TILE 2048

__global__ __launch_bounds__(256) void k_scan1(const int* __restrict__ deg,
                                               int* __restrict__ bsum, int n) {
    __shared__ int s[256];
    const int tid = threadIdx.x;
    const int base = blockIdx.x * SCAN_TILE + tid * 8;
    int sum = 0;
    if (base + 8 <= n) {
        int4 a = *reinterpret_cast<const int4*>(&deg[base]);
        int4 c = *reinterpret_cast<const int4*>(&deg[base + 4]);
        sum = a.x + a.y + a.z + a.w + c.x + c.y + c.z + c.w;
    } else {
#pragma unroll
        for (int i = 0; i < 8; ++i) { int idx = base + i; if (idx < n) sum += deg[idx]; }
    }
    s[tid] = sum;
    __syncthreads();
#pragma unroll
    for (int off = 128; off > 0; off >>= 1) {
        if (tid < off) s[tid] += s[tid + off];
        __syncthreads();
    }
    if (tid == 0) bsum[blockIdx.x] = s[0];
}

__global__ __launch_bounds__(256) void k_scan2(const int* __restrict__ bsum,
                                               int* __restrict__ bscan, int nb) {
    __shared__ int s[256];
    const int tid = threadIdx.x;
    s[tid] = (tid < nb) ? bsum[tid] : 0;
    __syncthreads();
#pragma unroll
    for (int off = 1; off < 256; off <<= 1) {
        int v = (tid >= off) ? s[tid - off] : 0;
        __syncthreads();
        s[tid] += v;
        __syncthreads();
    }
    if (tid < nb) bscan[tid] = (tid == 0) ? 0 : s[tid - 1];
}

__global__ __launch_bounds__(256) void k_scan3(const int* __restrict__ deg,
                                               const int* __restrict__ bscan,
                                               int* __restrict__ row_ptr,
                                               int n, int E) {
    __shared__ int s[256];
    const int tid = threadIdx.x;
    const int base = blockIdx.x * SCAN_TILE + tid * 8;
    int v[8];
    if (base + 8 <= n) {
        int4 a = *reinterpret_cast<const int4*>(&deg[base]);
        int4 c = *reinterpret_cast<const int4*>(&deg[base + 4]);
        v[0] = a.x; v[1] = a.y; v[2] = a.z; v[3] = a.w;
        v[4] = c.x; v[5] = c.y; v[6] = c.z; v[7] = c.w;
    } else {
#pragma unroll
        for (int i = 0; i < 8; ++i) { int idx = base + i; v[i] = (idx < n) ? deg[idx] : 0; }
    }
    int sum = 0;
#pragma unroll
    for (int i = 0; i < 8; ++i) sum += v[i];
    s[tid] = sum;
    __syncthreads();
#pragma unroll
    for (int off = 1; off < 256; off <<= 1) {
        int t = (tid >= off) ? s[tid - off] : 0;
        __syncthreads();
        s[tid] += t;
        __syncthreads();
    }
    int run = bscan[blockIdx.x] + ((tid == 0) ? 0 : s[tid - 1]);
#pragma unroll
    for (int i = 0; i < 8; ++i) {
        int idx = base + i;
        if (idx < n) {
            row_ptr[idx] = run;
            run += v[i];
        }
    }
    if (blockIdx.x == 0 && tid == 0) row_ptr[n] = E;
}

// --- binned scatter (fast path, requires n <= 65536 so col fits 16 bits and
//     nbuckets = ceil(n/128) <= 512 fits 9 bits) -------------------------------

#define BIN_TILE 4096
#define NBMAX    512

// bucket_fill[b] = row_ptr[128*b]  (start slot of bucket b's CSR span)
__global__ void k_binit(const int* __restrict__ row_ptr, int* __restrict__ bucket_fill,
                        int nbk) {
    int b = blockIdx.x * blockDim.x + threadIdx.x;
    if (b < nbk) bucket_fill[b] = row_ptr[b << 7];
}

// Phase A: bin edges into bucket regions of ept with LDS staging so global
// writes are coalesced runs. Record: .x = col | rowoff<<16 | bucket<<23, .y = w.
__global__ __launch_bounds__(256) void k_bin(const int* __restrict__ rows,
                                             const int* __restrict__ cols,
                                             const float* __restrict__ ew,
                                             int* __restrict__ bucket_fill,
                                             int2* __restrict__ ept, int E, int nbk) {
    __shared__ int cnt[NBMAX], inc[NBMAX], cnt2[NBMAX], gbase[NBMAX];
    __shared__ int2 stage[BIN_TILE];
    const int t = threadIdx.x;
    const int tile0 = blockIdx.x * BIN_TILE;

    cnt[t] = 0; cnt[t + 256] = 0; cnt2[t] = 0; cnt2[t + 256] = 0;
    __syncthreads();

    // load up to 16 edges (stride-256 => validity is a prefix), pack, histogram
    int px[16], pw[16];
    int nv = 0;
#pragma unroll
    for (int j = 0; j < 16; ++j) {
        int e = tile0 + t + j * 256;
        if (e < E) {
            int r = rows[e];
            int b = r >> 7;
            px[nv] = cols[e] | ((r & 127) << 16) | (b << 23);
            pw[nv] = __float_as_int(ew[e]);
            ++nv;
            atomicAdd(&cnt[b], 1);
        }
    }
    __syncthreads();

    // inclusive scan of cnt -> inc (512 entries, 256 threads own 2 each)
    inc[t] = cnt[t]; inc[t + 256] = cnt[t + 256];
    __syncthreads();
    for (int d = 1; d < NBMAX; d <<= 1) {
        int v0 = (t >= d) ? inc[t - d] : 0;
        int v1 = (t + 256 >= d) ? inc[t + 256 - d] : 0;
        __syncthreads();
        inc[t] += v0; inc[t + 256] += v1;
        __syncthreads();
    }

    // reserve this tile's run in each bucket's global region
    if (t < nbk && cnt[t] > 0)             gbase[t]       = atomicAdd(&bucket_fill[t], cnt[t]);
    if (t + 256 < nbk && cnt[t + 256] > 0) gbase[t + 256] = atomicAdd(&bucket_fill[t + 256], cnt[t + 256]);

    // stage records bucket-ordered in LDS
    for (int j = 0; j < nv; ++j) {
        int b = ((unsigned)px[j]) >> 23;
        int off = (b == 0) ? 0 : inc[b - 1];
        int r = atomicAdd(&cnt2[b], 1);
        stage[off + r] = make_int2(px[j], pw[j]);
    }
    __syncthreads();

    // flush: consecutive stage slots in a bucket -> consecutive global slots
    int total = inc[nbk - 1];
    for (int s = t; s < total; s += 256) {
        int2 rec = stage[s];
        int b = ((unsigned)rec.x) >> 23;
        int off = (b == 0) ? 0 : inc[b - 1];
        ept[gbase[b] + (s - off)] = rec;
    }
}

// Phase B: one block per bucket; final scatter confined to the bucket's
// contiguous CSR span (~32 KB) -> absorbed by that XCD's L2.
__global__ __launch_bounds__(256) void k_unbin(const int* __restrict__ row_ptr,
                                               const int2* __restrict__ ept,
                                               int2* __restrict__ ep, int n) {
    __shared__ int fill[128];
    const int b = blockIdx.x;
    const int t = threadIdx.x;
    const int r0 = b << 7;
    if (t < 128) {
        int rr = r0 + t;
        fill[t] = row_ptr[rr > n ? n : rr];
    }
    __syncthreads();
    int rend = r0 + 128; if (rend > n) rend = n;
    const int bstart = row_ptr[r0];
    const int bend   = row_ptr[rend];
    for (int e = bstart + t; e < bend; e += 256) {
        int2 rec = ept[e];
        int ro = (rec.x >> 16) & 127;
        int p = atomicAdd(&fill[ro], 1);
        ep[p] = make_int2(rec.x & 0xFFFF, rec.y);
    }
}

// --- fallback scatter for n > 65536 ----------------------------------------

__global__ void k_fillinit(const int* __restrict__ row_ptr, int* __restrict__ row_fill,
                           int n) {
    int i = blockIdx.x * blockDim.x + threadIdx.x;
    if (i < n) row_fill[i] = row_ptr[i];
}

__global__ void k_scatter(const int* __restrict__ rows, const int* __restrict__ cols,
                          const float* __restrict__ ew, int* __restrict__ row_fill,
                          int2* __restrict__ ep, int E) {
    int i = blockIdx.x * blockDim.x + threadIdx.x;
    if (i < E) {
        int r = rows[i];
        int p = atomicAdd(&row_fill[r], 1);
        ep[p] = make_int2(cols[i], __float_as_int(ew[i]));
    }
}

// ---------------------------------------------------------------------------
// Split-K tiled GEMM: P[ks][n x DC] partial = A[:, ks-chunk] @ W[ks-chunk, :]
// ---------------------------------------------------------------------------
template <int DK, int DC, int TN, int KCHUNK>
__global__ __launch_bounds__(256) void k_gemm(const float* __restrict__ A,
                                              const float* __restrict__ W,
                                              float* __restrict__ P, int n) {
    constexpr int BR = 128, BK = 16, TM = 8;
    constexpr int TX = DC / TN;
    static_assert(TX * (BR / TM) == 256, "thread layout");

    __shared__ float As[BK][BR];
    __shared__ float Ws[BK][DC];

    const int tid  = threadIdx.x;
    const int tx   = tid % TX;
    const int ty   = tid / TX;
    const int row0 = blockIdx.x * BR;
    const int kbeg = blockIdx.y * KCHUNK;
    float* __restrict__ Pp = P + (size_t)blockIdx.y * n * DC;

    float acc[TM][TN];
#pragma unroll
    for (int i = 0; i < TM; ++i)
#pragma unroll
        for (int j = 0; j < TN; ++j) acc[i][j] = 0.f;

    for (int k0 = kbeg; k0 < kbeg + KCHUNK; k0 += BK) {
        __syncthreads();
#pragma unroll
        for (int l = 0; l < 2; ++l) {
            int q   = tid + l * 256;
            int row = q & 127;
            int kq  = q >> 7;
            int rr  = row0 + row;
            if (rr >= n) rr = n - 1;
            float4 v = *reinterpret_cast<const float4*>(&A[(size_t)rr * DK + k0 + 4 * kq]);
            As[4 * kq + 0][row] = v.x;
            As[4 * kq + 1][row] = v.y;
            As[4 * kq + 2][row] = v.z;
            As[4 * kq + 3][row] = v.w;
        }
        constexpr int WL = (BK * DC / 4) / 256;
#pragma unroll
        for (int l = 0; l < WL; ++l) {
            int q = tid + l * 256;
            int k = (q * 4) / DC;
            int c = (q * 4) % DC;
            *reinterpret_cast<float4*>(&Ws[k][c]) =
                *reinterpret_cast<const float4*>(&W[(size_t)(k0 + k) * DC + c]);
        }
        __syncthreads();

#pragma unroll
        for (int k = 0; k < BK; ++k) {
            float a[TM], w[TN];
#pragma unroll
            for (int i = 0; i < TM; i += 4) {
                float4 v = *reinterpret_cast<const float4*>(&As[k][ty * TM + i]);
                a[i] = v.x; a[i + 1] = v.y; a[i + 2] = v.z; a[i + 3] = v.w;
            }
#pragma unroll
            for (int j = 0; j < TN; j += 4) {
                float4 v = *reinterpret_cast<const float4*>(&Ws[k][tx * TN + j]);
                w[j] = v.x; w[j + 1] = v.y; w[j + 2] = v.z; w[j + 3] = v.w;
            }
#pragma unroll
            for (int i = 0; i < TM; ++i)
#pragma unroll
                for (int j = 0; j < TN; ++j)
                    acc[i][j] = fmaf(a[i], w[j], acc[i][j]);
        }
    }

#pragma unroll
    for (int i = 0; i < TM; ++i) {
        int r = row0 + ty * TM + i;
        if (r < n) {
#pragma unroll
            for (int j = 0; j < TN; j += 4) {
                float4 v = make_float4(acc[i][j], acc[i][j + 1], acc[i][j + 2], acc[i][j + 3]);
                *reinterpret_cast<float4*>(&Pp[(size_t)r * DC + tx * TN + j]) = v;
            }
        }
    }
}

// dst[i] = sum_{s < ks} src[s*len + i], float4-vectorized. len % 4 == 0.
__global__ void k_combine(float* __restrict__ dst, const float* __restrict__ src,
                          size_t len, int ks) {
    size_t i = ((size_t)blockIdx.x * blockDim.x + threadIdx.x) * 4;
    if (i >= len) return;
    float4 a = *reinterpret_cast<const float4*>(&src[i]);
    for (int s = 1; s < ks; ++s) {
        float4 b = *reinterpret_cast<const float4*>(&src[s * len + i]);
        a.x += b.x; a.y += b.y; a.z += b.z; a.w += b.w;
    }
    *reinterpret_cast<float4*>(&dst[i]) = a;
}

// ---------------------------------------------------------------------------
// CSR SpMM, one WAVE per row. Lane covers the feature dim (float2 for D=128,
// float for D=64). Edge records are wave-uniform int2 loads. Unroll 4.
// ---------------------------------------------------------------------------
template <int D, bool RELU>
__global__ __launch_bounds__(256) void k_spmm(const int* __restrict__ rp,
                                              const int2* __restrict__ ep,
                                              const float* __restrict__ sup,
                                              const float* __restrict__ bias,
                                              float* __restrict__ out, int n) {
    const int w    = (blockIdx.x * 256 + threadIdx.x) >> 6;
    const int lane = threadIdx.x & 63;
    if (w >= n) return;
    const int s = rp[w], e = rp[w + 1];

    if constexpr (D == 128) {
        const int d = lane * 2;
        float2 acc = make_float2(0.f, 0.f);
        int i = s;
        for (; i + 4 <= e; i += 4) {
            int2 r0 = ep[i], r1 = ep[i + 1], r2 = ep[i + 2], r3 = ep[i + 3];
            float2 v0 = *reinterpret_cast<const float2*>(&sup[(size_t)r0.x * D + d]);
            float2 v1 = *reinterpret_cast<const float2*>(&sup[(size_t)r1.x * D + d]);
            float2 v2 = *reinterpret_cast<const float2*>(&sup[(size_t)r2.x * D + d]);
            float2 v3 = *reinterpret_cast<const float2*>(&sup[(size_t)r3.x * D + d]);
            float w0 = __int_as_float(r0.y), w1 = __int_as_float(r1.y);
            float w2 = __int_as_float(r2.y), w3 = __int_as_float(r3.y);
            acc.x = fmaf(w0, v0.x, acc.x); acc.y = fmaf(w0, v0.y, acc.y);
            acc.x = fmaf(w1, v1.x, acc.x); acc.y = fmaf(w1, v1.y, acc.y);
            acc.x = fmaf(w2, v2.x, acc.x); acc.y = fmaf(w2, v2.y, acc.y);
            acc.x = fmaf(w3, v3.x, acc.x); acc.y = fmaf(w3, v3.y, acc.y);
        }
        for (; i < e; ++i) {
            int2 r = ep[i];
            float2 v = *reinterpret_cast<const float2*>(&sup[(size_t)r.x * D + d]);
            float ww = __int_as_float(r.y);
            acc.x = fmaf(ww, v.x, acc.x); acc.y = fmaf(ww, v.y, acc.y);
        }
        float2 b = *reinterpret_cast<const float2*>(&bias[d]);
        acc.x += b.x; acc.y += b.y;
        if (RELU) { acc.x = fmaxf(acc.x, 0.f); acc.y = fmaxf(acc.y, 0.f); }
        *reinterpret_cast<float2*>(&out[(size_t)w * D + d]) = acc;
    } else {
        const int d = lane;
        float acc = 0.f;
        int i = s;
        for (; i + 4 <= e; i += 4) {
            int2 r0 = ep[i], r1 = ep[i + 1], r2 = ep[i + 2], r3 = ep[i + 3];
            float v0 = sup[(size_t)r0.x * D + d];
            float v1 = sup[(size_t)r1.x * D + d];
            float v2 = sup[(size_t)r2.x * D + d];
            float v3 = sup[(size_t)r3.x * D + d];
            acc = fmaf(__int_as_float(r0.y), v0, acc);
            acc = fmaf(__int_as_float(r1.y), v1, acc);
            acc = fmaf(__int_as_float(r2.y), v2, acc);
            acc = fmaf(__int_as_float(r3.y), v3, acc);
        }
        for (; i < e; ++i) {
            int2 r = ep[i];
            acc = fmaf(__int_as_float(r.y), sup[(size_t)r.x * D + d], acc);
        }
        acc += bias[d];
        if (RELU) acc = fmaxf(acc, 0.f);
        out[(size_t)w * D + d] = acc;
    }
}

// ---------------------------------------------------------------------------

extern "C" void kernel_launch(void* const* d_in, const int* in_sizes, int n_in,
                              void* d_out, int out_size, void* d_ws, size_t ws_size,
                              hipStream_t stream) {
    const float* x  = (const float*)d_in[0];
    const int*   ei = (const int*)d_in[1];
    const float* ew = (const float*)d_in[2];
    const float* W1 = (const float*)d_in[3];
    const float* b1 = (const float*)d_in[4];
    const float* W2 = (const float*)d_in[5];
    const float* b2 = (const float*)d_in[6];
    float* out = (float*)d_out;

    const int n = in_sizes[0] / IN_DIM;  // 50000
    const int E = in_sizes[2];           // 1600000
    const int* rows = ei;
    const int* cols = ei + E;

    char* ws = (char*)d_ws;
    size_t off = 0;
    auto alloc = [&](size_t bytes) -> void* {
        off = (off + 255) & ~(size_t)255;
        void* p = ws + off;
        off += bytes;
        return p;
    };
    int2*  ep       = (int2*)alloc((size_t)E * sizeof(int2));
    int*   deg      = (int*)alloc((size_t)n * sizeof(int));
    int*   row_ptr  = (int*)alloc((size_t)(n + 1) * sizeof(int));
    int*   row_fill = (int*)alloc((size_t)n * sizeof(int));     // fallback path only
    int*   bsum     = (int*)alloc(256 * sizeof(int));
    int*   bscan    = (int*)alloc(256 * sizeof(int));
    int*   bfill    = (int*)alloc(NBMAX * sizeof(int));
    float* sup1     = (float*)alloc((size_t)n * HID_DIM * sizeof(float));
    float* h        = (float*)alloc((size_t)n * HID_DIM * sizeof(float));
    float* sup2     = sup1;                 // sup1 dead after spmm1
    int2*  ept      = (int2*)sup1;          // bin temp aliases sup1 (dead until gemm1)

    // Split-K partials region (sized to fit ws)
    size_t fixed = (off + 255) & ~(size_t)255;
    size_t per_split1 = (size_t)n * HID_DIM * sizeof(float);
    size_t per_split2 = (size_t)n * OUT_DIM * sizeof(float);
    int KS1 = 1;
    if (fixed + 4 * per_split1 <= ws_size) KS1 = 4;
    else if (fixed + 2 * per_split1 <= ws_size) KS1 = 2;
    size_t pbytes = (KS1 > 1) ? KS1 * per_split1 : 0;
    if (pbytes < 2 * per_split2 && fixed + 2 * per_split2 <= ws_size)
        pbytes = 2 * per_split2;
    float* pbuf = (float*)alloc(pbytes);
    int KS2 = (pbytes >= 2 * per_split2) ? 2 : 1;

    float* p1 = (KS1 > 1) ? pbuf : sup1;
    float* p2 = (KS2 > 1) ? pbuf : sup2;

    const int gemm_rb = (n + 127) / 128;
    const int nb  = (n + SCAN_TILE - 1) / SCAN_TILE;  // scan blocks (25)
    const int nbk = (n + 127) / 128;                  // buckets (391)

    // --- CSR build ---
    k_zero<<<(n + 255) / 256, 256, 0, stream>>>(deg, n);
    k_hist<<<(E + 255) / 256, 256, 0, stream>>>(rows, deg, E);
    k_scan1<<<nb, 256, 0, stream>>>(deg, bsum, n);
    k_scan2<<<1, 256, 0, stream>>>(bsum, bscan, nb);
    k_scan3<<<nb, 256, 0, stream>>>(deg, bscan, row_ptr, n, E);

    if (n <= 65536) {   // binned two-phase scatter (col fits 16 bits, nbk <= 512)
        k_binit<<<(nbk + 255) / 256, 256, 0, stream>>>(row_ptr, bfill, nbk);
        k_bin<<<(E + BIN_TILE - 1) / BIN_TILE, 256, 0, stream>>>(rows, cols, ew, bfill, ept, E, nbk);
        k_unbin<<<nbk, 256, 0, stream>>>(row_ptr, ept, ep, n);
    } else {            // fallback: direct scatter
        k_fillinit<<<(n + 255) / 256, 256, 0, stream>>>(row_ptr, row_fill, n);
        k_scatter<<<(E + 255) / 256, 256, 0, stream>>>(rows, cols, ew, row_fill, ep, E);
    }

    // --- Layer 1 ---
    {
        dim3 g(gemm_rb, KS1);
        if (KS1 == 4)
            k_gemm<IN_DIM, HID_DIM, 8, IN_DIM / 4><<<g, 256, 0, stream>>>(x, W1, p1, n);
        else if (KS1 == 2)
            k_gemm<IN_DIM, HID_DIM, 8, IN_DIM / 2><<<g, 256, 0, stream>>>(x, W1, p1, n);
        else
            k_gemm<IN_DIM, HID_DIM, 8, IN_DIM><<<g, 256, 0, stream>>>(x, W1, p1, n);
        if (KS1 > 1) {
            size_t len = (size_t)n * HID_DIM;
            k_combine<<<(int)((len / 4 + 255) / 256), 256, 0, stream>>>(sup1, p1, len, KS1);
        }
    }
    k_spmm<HID_DIM, true><<<(n + 3) / 4, 256, 0, stream>>>(row_ptr, ep, sup1, b1, h, n);

    // --- Layer 2 ---
    {
        dim3 g(gemm_rb, KS2);
        if (KS2 == 2)
            k_gemm<HID_DIM, OUT_DIM, 4, HID_DIM / 2><<<g, 256, 0, stream>>>(h, W2, p2, n);
        else
            k_gemm<HID_DIM, OUT_DIM, 4, HID_DIM><<<g, 256, 0, stream>>>(h, W2, p2, n);
        if (KS2 > 1) {
            size_t len = (size_t)n * OUT_DIM;
            k_combine<<<(int)((len / 4 + 255) / 256), 256, 0, stream>>>(sup2, p2, len, KS2);
        }
    }
    k_spmm<OUT_DIM, false><<<(n + 3) / 4, 256, 0, stream>>>(row_ptr, ep, sup2, b2, out, n);
}

// Round 6
// 469.980 us; speedup vs baseline: 1.5914x; 1.1843x over previous
//
#include <hip/hip_runtime.h>

// Problem constants: N=50000, E=1.6M, dims 512 -> 128 -> 64
#define IN_DIM  512
#define HID_DIM 128
#define OUT_DIM 64

typedef unsigned short ushort_t;
typedef ushort_t ushort8 __attribute__((ext_vector_type(8)));
typedef __bf16  bf16x8  __attribute__((ext_vector_type(8)));
typedef float   floatx4 __attribute__((ext_vector_type(4)));

// fp32 -> bf16 round-to-nearest-even (bit trick; inputs are finite)
__device__ __forceinline__ ushort_t f2bf(float f) {
    union { float f; unsigned u; } v; v.f = f;
    unsigned r = v.u + 0x7FFFu + ((v.u >> 16) & 1u);
    return (ushort_t)(r >> 16);
}

// ---------------------------------------------------------------------------
// CSR build: degree histogram -> reduce-then-scan -> binned two-phase scatter
// ---------------------------------------------------------------------------

__global__ void k_zero(int* __restrict__ p, int n) {
    int i = blockIdx.x * blockDim.x + threadIdx.x;
    if (i < n) p[i] = 0;
}

__global__ void k_hist(const int* __restrict__ rows, int* __restrict__ deg, int E) {
    int i = blockIdx.x * blockDim.x + threadIdx.x;
    if (i < E) atomicAdd(&deg[rows[i]], 1);
}

#define SCAN_TILE 2048

__global__ __launch_bounds__(256) void k_scan1(const int* __restrict__ deg,
                                               int* __restrict__ bsum, int n) {
    __shared__ int s[256];
    const int tid = threadIdx.x;
    const int base = blockIdx.x * SCAN_TILE + tid * 8;
    int sum = 0;
    if (base + 8 <= n) {
        int4 a = *reinterpret_cast<const int4*>(&deg[base]);
        int4 c = *reinterpret_cast<const int4*>(&deg[base + 4]);
        sum = a.x + a.y + a.z + a.w + c.x + c.y + c.z + c.w;
    } else {
#pragma unroll
        for (int i = 0; i < 8; ++i) { int idx = base + i; if (idx < n) sum += deg[idx]; }
    }
    s[tid] = sum;
    __syncthreads();
#pragma unroll
    for (int off = 128; off > 0; off >>= 1) {
        if (tid < off) s[tid] += s[tid + off];
        __syncthreads();
    }
    if (tid == 0) bsum[blockIdx.x] = s[0];
}

__global__ __launch_bounds__(256) void k_scan2(const int* __restrict__ bsum,
                                               int* __restrict__ bscan, int nb) {
    __shared__ int s[256];
    const int tid = threadIdx.x;
    s[tid] = (tid < nb) ? bsum[tid] : 0;
    __syncthreads();
#pragma unroll
    for (int off = 1; off < 256; off <<= 1) {
        int v = (tid >= off) ? s[tid - off] : 0;
        __syncthreads();
        s[tid] += v;
        __syncthreads();
    }
    if (tid < nb) bscan[tid] = (tid == 0) ? 0 : s[tid - 1];
}

__global__ __launch_bounds__(256) void k_scan3(const int* __restrict__ deg,
                                               const int* __restrict__ bscan,
                                               int* __restrict__ row_ptr,
                                               int n, int E) {
    __shared__ int s[256];
    const int tid = threadIdx.x;
    const int base = blockIdx.x * SCAN_TILE + tid * 8;
    int v[8];
    if (base + 8 <= n) {
        int4 a = *reinterpret_cast<const int4*>(&deg[base]);
        int4 c = *reinterpret_cast<const int4*>(&deg[base + 4]);
        v[0] = a.x; v[1] = a.y; v[2] = a.z; v[3] = a.w;
        v[4] = c.x; v[5] = c.y; v[6] = c.z; v[7] = c.w;
    } else {
#pragma unroll
        for (int i = 0; i < 8; ++i) { int idx = base + i; v[i] = (idx < n) ? deg[idx] : 0; }
    }
    int sum = 0;
#pragma unroll
    for (int i = 0; i < 8; ++i) sum += v[i];
    s[tid] = sum;
    __syncthreads();
#pragma unroll
    for (int off = 1; off < 256; off <<= 1) {
        int t = (tid >= off) ? s[tid - off] : 0;
        __syncthreads();
        s[tid] += t;
        __syncthreads();
    }
    int run = bscan[blockIdx.x] + ((tid == 0) ? 0 : s[tid - 1]);
#pragma unroll
    for (int i = 0; i < 8; ++i) {
        int idx = base + i;
        if (idx < n) {
            row_ptr[idx] = run;
            run += v[i];
        }
    }
    if (blockIdx.x == 0 && tid == 0) row_ptr[n] = E;
}

#define BIN_TILE 4096
#define NBMAX    512

__global__ void k_binit(const int* __restrict__ row_ptr, int* __restrict__ bucket_fill,
                        int nbk) {
    int b = blockIdx.x * blockDim.x + threadIdx.x;
    if (b < nbk) bucket_fill[b] = row_ptr[b << 7];
}

__global__ __launch_bounds__(256) void k_bin(const int* __restrict__ rows,
                                             const int* __restrict__ cols,
                                             const float* __restrict__ ew,
                                             int* __restrict__ bucket_fill,
                                             int2* __restrict__ ept, int E, int nbk) {
    __shared__ int cnt[NBMAX], inc[NBMAX], cnt2[NBMAX], gbase[NBMAX];
    __shared__ int2 stage[BIN_TILE];
    const int t = threadIdx.x;
    const int tile0 = blockIdx.x * BIN_TILE;

    cnt[t] = 0; cnt[t + 256] = 0; cnt2[t] = 0; cnt2[t + 256] = 0;
    __syncthreads();

    int px[16], pw[16];
    int nv = 0;
#pragma unroll
    for (int j = 0; j < 16; ++j) {
        int e = tile0 + t + j * 256;
        if (e < E) {
            int r = rows[e];
            int b = r >> 7;
            px[nv] = cols[e] | ((r & 127) << 16) | (b << 23);
            pw[nv] = __float_as_int(ew[e]);
            ++nv;
            atomicAdd(&cnt[b], 1);
        }
    }
    __syncthreads();

    inc[t] = cnt[t]; inc[t + 256] = cnt[t + 256];
    __syncthreads();
    for (int d = 1; d < NBMAX; d <<= 1) {
        int v0 = (t >= d) ? inc[t - d] : 0;
        int v1 = (t + 256 >= d) ? inc[t + 256 - d] : 0;
        __syncthreads();
        inc[t] += v0; inc[t + 256] += v1;
        __syncthreads();
    }

    if (t < nbk && cnt[t] > 0)             gbase[t]       = atomicAdd(&bucket_fill[t], cnt[t]);
    if (t + 256 < nbk && cnt[t + 256] > 0) gbase[t + 256] = atomicAdd(&bucket_fill[t + 256], cnt[t + 256]);

    for (int j = 0; j < nv; ++j) {
        int b = ((unsigned)px[j]) >> 23;
        int off = (b == 0) ? 0 : inc[b - 1];
        int r = atomicAdd(&cnt2[b], 1);
        stage[off + r] = make_int2(px[j], pw[j]);
    }
    __syncthreads();

    int total = inc[nbk - 1];
    for (int s = t; s < total; s += 256) {
        int2 rec = stage[s];
        int b = ((unsigned)rec.x) >> 23;
        int off = (b == 0) ? 0 : inc[b - 1];
        ept[gbase[b] + (s - off)] = rec;
    }
}

__global__ __launch_bounds__(256) void k_unbin(const int* __restrict__ row_ptr,
                                               const int2* __restrict__ ept,
                                               int2* __restrict__ ep, int n) {
    __shared__ int fill[128];
    const int b = blockIdx.x;
    const int t = threadIdx.x;
    const int r0 = b << 7;
    if (t < 128) {
        int rr = r0 + t;
        fill[t] = row_ptr[rr > n ? n : rr];
    }
    __syncthreads();
    int rend = r0 + 128; if (rend > n) rend = n;
    const int bstart = row_ptr[r0];
    const int bend   = row_ptr[rend];
    for (int e = bstart + t; e < bend; e += 256) {
        int2 rec = ept[e];
        int ro = (rec.x >> 16) & 127;
        int p = atomicAdd(&fill[ro], 1);
        ep[p] = make_int2(rec.x & 0xFFFF, rec.y);
    }
}

// fallback for n > 65536
__global__ void k_fillinit(const int* __restrict__ row_ptr, int* __restrict__ row_fill,
                           int n) {
    int i = blockIdx.x * blockDim.x + threadIdx.x;
    if (i < n) row_fill[i] = row_ptr[i];
}

__global__ void k_scatter(const int* __restrict__ rows, const int* __restrict__ cols,
                          const float* __restrict__ ew, int* __restrict__ row_fill,
                          int2* __restrict__ ep, int E) {
    int i = blockIdx.x * blockDim.x + threadIdx.x;
    if (i < E) {
        int r = rows[i];
        int p = atomicAdd(&row_fill[r], 1);
        ep[p] = make_int2(cols[i], __float_as_int(ew[i]));
    }
}

// ---------------------------------------------------------------------------
// Weight transpose + bf16 convert: W[DK x DC] fp32 -> Wt[DC x DK] bf16
// Tiny (<=64K elements); coalesced read, scattered 2B writes absorbed by L2.
// ---------------------------------------------------------------------------
__global__ void k_wcvt(const float* __restrict__ W, ushort_t* __restrict__ Wt,
                       int DKd, int DCd) {
    int i = blockIdx.x * blockDim.x + threadIdx.x;
    if (i < DKd * DCd) {
        int k = i / DCd, c = i % DCd;
        Wt[(size_t)c * DKd + k] = f2bf(W[i]);
    }
}

// ---------------------------------------------------------------------------
// MFMA bf16 GEMM: C[n x DC] = A[n x DK] @ W[DK x DC], fp32 accumulate.
// Block: 256 threads (4 waves), 64-row tile; wave w owns rows w*16..w*16+15.
// K-loop: BK=32 per iter. A (fp32) converted to bf16 during LDS staging;
// W pre-transposed bf16 (Wt[c][k]) so both frags are contiguous ds_read_b128.
// LDS rows padded to 40 bf16 (80 B) to break 64B-stride bank conflicts.
// Frag layouts (verified m89/m120): A/B [dim=lane&15][k=quad*8+j];
// C/D col=lane&15, row=quad*4+reg.
// ---------------------------------------------------------------------------
template <int DK, int DC>
__global__ __launch_bounds__(256) void k_gemm_mfma(const float* __restrict__ A,
                                                   const ushort_t* __restrict__ Wt,
                                                   float* __restrict__ C, int n) {
    constexpr int BR = 64, BK = 32, NT = DC / 16, SA = 40;
    __shared__ __align__(16) ushort_t As[BR * SA];
    __shared__ __align__(16) ushort_t Ws[DC * SA];

    const int tid  = threadIdx.x;
    const int w    = tid >> 6;
    const int lane = tid & 63;
    const int m    = lane & 15;
    const int quad = lane >> 4;
    const int row0 = blockIdx.x * BR;

    floatx4 acc[NT];
#pragma unroll
    for (int t = 0; t < NT; ++t) acc[t] = (floatx4){0.f, 0.f, 0.f, 0.f};

    // A staging map: thread -> (row, k-offset of 8)
    const int ar = tid >> 2;          // 0..63
    const int ak = (tid & 3) * 8;     // 0,8,16,24
    int arr = row0 + ar; if (arr >= n) arr = n - 1;   // clamp; dup discarded at store
    const float* Ab = A + (size_t)arr * DK;

    for (int k0 = 0; k0 < DK; k0 += BK) {
        __syncthreads();   // previous iter's LDS reads done

        // --- stage A tile (fp32 -> bf16) ---
        float4 a0 = *reinterpret_cast<const float4*>(Ab + k0 + ak);
        float4 a1 = *reinterpret_cast<const float4*>(Ab + k0 + ak + 4);
        ushort8 ap = { f2bf(a0.x), f2bf(a0.y), f2bf(a0.z), f2bf(a0.w),
                       f2bf(a1.x), f2bf(a1.y), f2bf(a1.z), f2bf(a1.w) };
        *reinterpret_cast<ushort8*>(&As[ar * SA + ak]) = ap;

        // --- stage W tile (already bf16, transposed) ---
        if constexpr (DC == 128) {
            int c = tid >> 1, koff = (tid & 1) * 16;
            ushort8 w0 = *reinterpret_cast<const ushort8*>(&Wt[(size_t)c * DK + k0 + koff]);
            ushort8 w1 = *reinterpret_cast<const ushort8*>(&Wt[(size_t)c * DK + k0 + koff + 8]);
            *reinterpret_cast<ushort8*>(&Ws[c * SA + koff])     = w0;
            *reinterpret_cast<ushort8*>(&Ws[c * SA + koff + 8]) = w1;
        } else {  // DC == 64
            int c = tid >> 2, koff = (tid & 3) * 8;
            ushort8 w0 = *reinterpret_cast<const ushort8*>(&Wt[(size_t)c * DK + k0 + koff]);
            *reinterpret_cast<ushort8*>(&Ws[c * SA + koff]) = w0;
        }
        __syncthreads();

        // --- MFMA ---
        bf16x8 a = *reinterpret_cast<bf16x8*>(&As[(w * 16 + m) * SA + quad * 8]);
#pragma unroll
        for (int t = 0; t < NT; ++t) {
            bf16x8 b = *reinterpret_cast<bf16x8*>(&Ws[(t * 16 + m) * SA + quad * 8]);
            acc[t] = __builtin_amdgcn_mfma_f32_16x16x32_bf16(a, b, acc[t], 0, 0, 0);
        }
    }

    // --- store: D col = lane&15, row = quad*4 + i ---
#pragma unroll
    for (int t = 0; t < NT; ++t) {
#pragma unroll
        for (int i = 0; i < 4; ++i) {
            int r = row0 + w * 16 + quad * 4 + i;
            if (r < n) C[(size_t)r * DC + t * 16 + m] = acc[t][i];
        }
    }
}

// ---------------------------------------------------------------------------
// CSR SpMM, one WAVE per row (float2 lanes for D=128, float for D=64).
// ---------------------------------------------------------------------------
template <int D, bool RELU>
__global__ __launch_bounds__(256) void k_spmm(const int* __restrict__ rp,
                                              const int2* __restrict__ ep,
                                              const float* __restrict__ sup,
                                              const float* __restrict__ bias,
                                              float* __restrict__ out, int n) {
    const int w    = (blockIdx.x * 256 + threadIdx.x) >> 6;
    const int lane = threadIdx.x & 63;
    if (w >= n) return;
    const int s = rp[w], e = rp[w + 1];

    if constexpr (D == 128) {
        const int d = lane * 2;
        float2 acc = make_float2(0.f, 0.f);
        int i = s;
        for (; i + 4 <= e; i += 4) {
            int2 r0 = ep[i], r1 = ep[i + 1], r2 = ep[i + 2], r3 = ep[i + 3];
            float2 v0 = *reinterpret_cast<const float2*>(&sup[(size_t)r0.x * D + d]);
            float2 v1 = *reinterpret_cast<const float2*>(&sup[(size_t)r1.x * D + d]);
            float2 v2 = *reinterpret_cast<const float2*>(&sup[(size_t)r2.x * D + d]);
            float2 v3 = *reinterpret_cast<const float2*>(&sup[(size_t)r3.x * D + d]);
            float w0 = __int_as_float(r0.y), w1 = __int_as_float(r1.y);
            float w2 = __int_as_float(r2.y), w3 = __int_as_float(r3.y);
            acc.x = fmaf(w0, v0.x, acc.x); acc.y = fmaf(w0, v0.y, acc.y);
            acc.x = fmaf(w1, v1.x, acc.x); acc.y = fmaf(w1, v1.y, acc.y);
            acc.x = fmaf(w2, v2.x, acc.x); acc.y = fmaf(w2, v2.y, acc.y);
            acc.x = fmaf(w3, v3.x, acc.x); acc.y = fmaf(w3, v3.y, acc.y);
        }
        for (; i < e; ++i) {
            int2 r = ep[i];
            float2 v = *reinterpret_cast<const float2*>(&sup[(size_t)r.x * D + d]);
            float ww = __int_as_float(r.y);
            acc.x = fmaf(ww, v.x, acc.x); acc.y = fmaf(ww, v.y, acc.y);
        }
        float2 b = *reinterpret_cast<const float2*>(&bias[d]);
        acc.x += b.x; acc.y += b.y;
        if (RELU) { acc.x = fmaxf(acc.x, 0.f); acc.y = fmaxf(acc.y, 0.f); }
        *reinterpret_cast<float2*>(&out[(size_t)w * D + d]) = acc;
    } else {
        const int d = lane;
        float acc = 0.f;
        int i = s;
        for (; i + 4 <= e; i += 4) {
            int2 r0 = ep[i], r1 = ep[i + 1], r2 = ep[i + 2], r3 = ep[i + 3];
            float v0 = sup[(size_t)r0.x * D + d];
            float v1 = sup[(size_t)r1.x * D + d];
            float v2 = sup[(size_t)r2.x * D + d];
            float v3 = sup[(size_t)r3.x * D + d];
            acc = fmaf(__int_as_float(r0.y), v0, acc);
            acc = fmaf(__int_as_float(r1.y), v1, acc);
            acc = fmaf(__int_as_float(r2.y), v2, acc);
            acc = fmaf(__int_as_float(r3.y), v3, acc);
        }
        for (; i < e; ++i) {
            int2 r = ep[i];
            acc = fmaf(__int_as_float(r.y), sup[(size_t)r.x * D + d], acc);
        }
        acc += bias[d];
        if (RELU) acc = fmaxf(acc, 0.f);
        out[(size_t)w * D + d] = acc;
    }
}

// ---------------------------------------------------------------------------

extern "C" void kernel_launch(void* const* d_in, const int* in_sizes, int n_in,
                              void* d_out, int out_size, void* d_ws, size_t ws_size,
                              hipStream_t stream) {
    const float* x  = (const float*)d_in[0];
    const int*   ei = (const int*)d_in[1];
    const float* ew = (const float*)d_in[2];
    const float* W1 = (const float*)d_in[3];
    const float* b1 = (const float*)d_in[4];
    const float* W2 = (const float*)d_in[5];
    const float* b2 = (const float*)d_in[6];
    float* out = (float*)d_out;

    const int n = in_sizes[0] / IN_DIM;  // 50000
    const int E = in_sizes[2];           // 1600000
    const int* rows = ei;
    const int* cols = ei + E;

    char* ws = (char*)d_ws;
    size_t off = 0;
    auto alloc = [&](size_t bytes) -> void* {
        off = (off + 255) & ~(size_t)255;
        void* p = ws + off;
        off += bytes;
        return p;
    };
    int2*     ep       = (int2*)alloc((size_t)E * sizeof(int2));
    int*      deg      = (int*)alloc((size_t)n * sizeof(int));
    int*      row_ptr  = (int*)alloc((size_t)(n + 1) * sizeof(int));
    int*      row_fill = (int*)alloc((size_t)n * sizeof(int));   // fallback only
    int*      bsum     = (int*)alloc(256 * sizeof(int));
    int*      bscan    = (int*)alloc(256 * sizeof(int));
    int*      bfill    = (int*)alloc(NBMAX * sizeof(int));
    ushort_t* Wt1      = (ushort_t*)alloc((size_t)IN_DIM * HID_DIM * sizeof(ushort_t));
    ushort_t* Wt2      = (ushort_t*)alloc((size_t)HID_DIM * OUT_DIM * sizeof(ushort_t));
    float*    sup1     = (float*)alloc((size_t)n * HID_DIM * sizeof(float));
    float*    h        = (float*)alloc((size_t)n * HID_DIM * sizeof(float));
    float*    sup2     = sup1;            // sup1 dead after spmm1
    int2*     ept      = (int2*)sup1;     // bin temp aliases sup1 (dead until gemm1)

    const int nb  = (n + SCAN_TILE - 1) / SCAN_TILE;
    const int nbk = (n + 127) / 128;
    const int gemm_b = (n + 63) / 64;

    // --- weight prep (independent of CSR) ---
    k_wcvt<<<(IN_DIM * HID_DIM + 255) / 256, 256, 0, stream>>>(W1, Wt1, IN_DIM, HID_DIM);
    k_wcvt<<<(HID_DIM * OUT_DIM + 255) / 256, 256, 0, stream>>>(W2, Wt2, HID_DIM, OUT_DIM);

    // --- CSR build ---
    k_zero<<<(n + 255) / 256, 256, 0, stream>>>(deg, n);
    k_hist<<<(E + 255) / 256, 256, 0, stream>>>(rows, deg, E);
    k_scan1<<<nb, 256, 0, stream>>>(deg, bsum, n);
    k_scan2<<<1, 256, 0, stream>>>(bsum, bscan, nb);
    k_scan3<<<nb, 256, 0, stream>>>(deg, bscan, row_ptr, n, E);

    if (n <= 65536) {
        k_binit<<<(nbk + 255) / 256, 256, 0, stream>>>(row_ptr, bfill, nbk);
        k_bin<<<(E + BIN_TILE - 1) / BIN_TILE, 256, 0, stream>>>(rows, cols, ew, bfill, ept, E, nbk);
        k_unbin<<<nbk, 256, 0, stream>>>(row_ptr, ept, ep, n);
    } else {
        k_fillinit<<<(n + 255) / 256, 256, 0, stream>>>(row_ptr, row_fill, n);
        k_scatter<<<(E + 255) / 256, 256, 0, stream>>>(rows, cols, ew, row_fill, ep, E);
    }

    // --- Layer 1 ---
    k_gemm_mfma<IN_DIM, HID_DIM><<<gemm_b, 256, 0, stream>>>(x, Wt1, sup1, n);
    k_spmm<HID_DIM, true><<<(n + 3) / 4, 256, 0, stream>>>(row_ptr, ep, sup1, b1, h, n);

    // --- Layer 2 ---
    k_gemm_mfma<HID_DIM, OUT_DIM><<<gemm_b, 256, 0, stream>>>(h, Wt2, sup2, n);
    k_spmm<OUT_DIM, false><<<(n + 3) / 4, 256, 0, stream>>>(row_ptr, ep, sup2, b2, out, n);
}

// Round 7
// 422.946 us; speedup vs baseline: 1.7684x; 1.1112x over previous
//
#include <hip/hip_runtime.h>

// Problem constants: N=50000, E=1.6M, dims 512 -> 128 -> 64
#define IN_DIM  512
#define HID_DIM 128
#define OUT_DIM 64

typedef unsigned short ushort_t;
typedef ushort_t ushort8 __attribute__((ext_vector_type(8)));
typedef __bf16  bf16x8  __attribute__((ext_vector_type(8)));
typedef float   floatx4 __attribute__((ext_vector_type(4)));

// fp32 -> bf16 round-to-nearest-even (bit trick; inputs are finite)
__device__ __forceinline__ ushort_t f2bf(float f) {
    union { float f; unsigned u; } v; v.f = f;
    unsigned r = v.u + 0x7FFFu + ((v.u >> 16) & 1u);
    return (ushort_t)(r >> 16);
}
__device__ __forceinline__ float bf2f(ushort_t u) {
    return __uint_as_float(((unsigned)u) << 16);
}

// ---------------------------------------------------------------------------
// CSR build: degree histogram -> reduce-then-scan -> binned two-phase scatter
// ---------------------------------------------------------------------------

__global__ void k_zero(int* __restrict__ p, int n) {
    int i = blockIdx.x * blockDim.x + threadIdx.x;
    if (i < n) p[i] = 0;
}

__global__ void k_hist(const int* __restrict__ rows, int* __restrict__ deg, int E) {
    int i = blockIdx.x * blockDim.x + threadIdx.x;
    if (i < E) atomicAdd(&deg[rows[i]], 1);
}

#define SCAN_TILE 2048

__global__ __launch_bounds__(256) void k_scan1(const int* __restrict__ deg,
                                               int* __restrict__ bsum, int n) {
    __shared__ int s[256];
    const int tid = threadIdx.x;
    const int base = blockIdx.x * SCAN_TILE + tid * 8;
    int sum = 0;
    if (base + 8 <= n) {
        int4 a = *reinterpret_cast<const int4*>(&deg[base]);
        int4 c = *reinterpret_cast<const int4*>(&deg[base + 4]);
        sum = a.x + a.y + a.z + a.w + c.x + c.y + c.z + c.w;
    } else {
#pragma unroll
        for (int i = 0; i < 8; ++i) { int idx = base + i; if (idx < n) sum += deg[idx]; }
    }
    s[tid] = sum;
    __syncthreads();
#pragma unroll
    for (int off = 128; off > 0; off >>= 1) {
        if (tid < off) s[tid] += s[tid + off];
        __syncthreads();
    }
    if (tid == 0) bsum[blockIdx.x] = s[0];
}

__global__ __launch_bounds__(256) void k_scan2(const int* __restrict__ bsum,
                                               int* __restrict__ bscan, int nb) {
    __shared__ int s[256];
    const int tid = threadIdx.x;
    s[tid] = (tid < nb) ? bsum[tid] : 0;
    __syncthreads();
#pragma unroll
    for (int off = 1; off < 256; off <<= 1) {
        int v = (tid >= off) ? s[tid - off] : 0;
        __syncthreads();
        s[tid] += v;
        __syncthreads();
    }
    if (tid < nb) bscan[tid] = (tid == 0) ? 0 : s[tid - 1];
}

__global__ __launch_bounds__(256) void k_scan3(const int* __restrict__ deg,
                                               const int* __restrict__ bscan,
                                               int* __restrict__ row_ptr,
                                               int n, int E) {
    __shared__ int s[256];
    const int tid = threadIdx.x;
    const int base = blockIdx.x * SCAN_TILE + tid * 8;
    int v[8];
    if (base + 8 <= n) {
        int4 a = *reinterpret_cast<const int4*>(&deg[base]);
        int4 c = *reinterpret_cast<const int4*>(&deg[base + 4]);
        v[0] = a.x; v[1] = a.y; v[2] = a.z; v[3] = a.w;
        v[4] = c.x; v[5] = c.y; v[6] = c.z; v[7] = c.w;
    } else {
#pragma unroll
        for (int i = 0; i < 8; ++i) { int idx = base + i; v[i] = (idx < n) ? deg[idx] : 0; }
    }
    int sum = 0;
#pragma unroll
    for (int i = 0; i < 8; ++i) sum += v[i];
    s[tid] = sum;
    __syncthreads();
#pragma unroll
    for (int off = 1; off < 256; off <<= 1) {
        int t = (tid >= off) ? s[tid - off] : 0;
        __syncthreads();
        s[tid] += t;
        __syncthreads();
    }
    int run = bscan[blockIdx.x] + ((tid == 0) ? 0 : s[tid - 1]);
#pragma unroll
    for (int i = 0; i < 8; ++i) {
        int idx = base + i;
        if (idx < n) {
            row_ptr[idx] = run;
            run += v[i];
        }
    }
    if (blockIdx.x == 0 && tid == 0) row_ptr[n] = E;
}

#define BIN_TILE 4096
#define NBMAX    512

__global__ void k_binit(const int* __restrict__ row_ptr, int* __restrict__ bucket_fill,
                        int nbk) {
    int b = blockIdx.x * blockDim.x + threadIdx.x;
    if (b < nbk) bucket_fill[b] = row_ptr[b << 7];
}

__global__ __launch_bounds__(256) void k_bin(const int* __restrict__ rows,
                                             const int* __restrict__ cols,
                                             const float* __restrict__ ew,
                                             int* __restrict__ bucket_fill,
                                             int2* __restrict__ ept, int E, int nbk) {
    __shared__ int cnt[NBMAX], inc[NBMAX], cnt2[NBMAX], gbase[NBMAX];
    __shared__ int2 stage[BIN_TILE];
    const int t = threadIdx.x;
    const int tile0 = blockIdx.x * BIN_TILE;

    cnt[t] = 0; cnt[t + 256] = 0; cnt2[t] = 0; cnt2[t + 256] = 0;
    __syncthreads();

    int px[16], pw[16];
    int nv = 0;
#pragma unroll
    for (int j = 0; j < 16; ++j) {
        int e = tile0 + t + j * 256;
        if (e < E) {
            int r = rows[e];
            int b = r >> 7;
            px[nv] = cols[e] | ((r & 127) << 16) | (b << 23);
            pw[nv] = __float_as_int(ew[e]);
            ++nv;
            atomicAdd(&cnt[b], 1);
        }
    }
    __syncthreads();

    inc[t] = cnt[t]; inc[t + 256] = cnt[t + 256];
    __syncthreads();
    for (int d = 1; d < NBMAX; d <<= 1) {
        int v0 = (t >= d) ? inc[t - d] : 0;
        int v1 = (t + 256 >= d) ? inc[t + 256 - d] : 0;
        __syncthreads();
        inc[t] += v0; inc[t + 256] += v1;
        __syncthreads();
    }

    if (t < nbk && cnt[t] > 0)             gbase[t]       = atomicAdd(&bucket_fill[t], cnt[t]);
    if (t + 256 < nbk && cnt[t + 256] > 0) gbase[t + 256] = atomicAdd(&bucket_fill[t + 256], cnt[t + 256]);

    for (int j = 0; j < nv; ++j) {
        int b = ((unsigned)px[j]) >> 23;
        int off = (b == 0) ? 0 : inc[b - 1];
        int r = atomicAdd(&cnt2[b], 1);
        stage[off + r] = make_int2(px[j], pw[j]);
    }
    __syncthreads();

    int total = inc[nbk - 1];
    for (int s = t; s < total; s += 256) {
        int2 rec = stage[s];
        int b = ((unsigned)rec.x) >> 23;
        int off = (b == 0) ? 0 : inc[b - 1];
        ept[gbase[b] + (s - off)] = rec;
    }
}

__global__ __launch_bounds__(256) void k_unbin(const int* __restrict__ row_ptr,
                                               const int2* __restrict__ ept,
                                               int2* __restrict__ ep, int n) {
    __shared__ int fill[128];
    const int b = blockIdx.x;
    const int t = threadIdx.x;
    const int r0 = b << 7;
    if (t < 128) {
        int rr = r0 + t;
        fill[t] = row_ptr[rr > n ? n : rr];
    }
    __syncthreads();
    int rend = r0 + 128; if (rend > n) rend = n;
    const int bstart = row_ptr[r0];
    const int bend   = row_ptr[rend];
    for (int e = bstart + t; e < bend; e += 256) {
        int2 rec = ept[e];
        int ro = (rec.x >> 16) & 127;
        int p = atomicAdd(&fill[ro], 1);
        ep[p] = make_int2(rec.x & 0xFFFF, rec.y);
    }
}

// fallback for n > 65536
__global__ void k_fillinit(const int* __restrict__ row_ptr, int* __restrict__ row_fill,
                           int n) {
    int i = blockIdx.x * blockDim.x + threadIdx.x;
    if (i < n) row_fill[i] = row_ptr[i];
}

__global__ void k_scatter(const int* __restrict__ rows, const int* __restrict__ cols,
                          const float* __restrict__ ew, int* __restrict__ row_fill,
                          int2* __restrict__ ep, int E) {
    int i = blockIdx.x * blockDim.x + threadIdx.x;
    if (i < E) {
        int r = rows[i];
        int p = atomicAdd(&row_fill[r], 1);
        ep[p] = make_int2(cols[i], __float_as_int(ew[i]));
    }
}

// ---------------------------------------------------------------------------
// Weight transpose + bf16 convert: W[DK x DC] fp32 -> Wt[DC x DK] bf16
// ---------------------------------------------------------------------------
__global__ void k_wcvt(const float* __restrict__ W, ushort_t* __restrict__ Wt,
                       int DKd, int DCd) {
    int i = blockIdx.x * blockDim.x + threadIdx.x;
    if (i < DKd * DCd) {
        int k = i / DCd, c = i % DCd;
        Wt[(size_t)c * DKd + k] = f2bf(W[i]);
    }
}

// ---------------------------------------------------------------------------
// MFMA bf16 GEMM: C[n x DC] (bf16) = A[n x DK] @ W[DK x DC], fp32 accumulate.
// A is fp32 (A_BF16=false, converted during staging) or bf16 (A_BF16=true).
// Block: 256 threads (4 waves), 64-row tile; wave w owns rows w*16..w*16+15.
// LDS rows padded to 40 bf16 (80 B) to break 64B-stride bank conflicts.
// Frag layouts (verified m89/m120): A/B [dim=lane&15][k=quad*8+j];
// C/D col=lane&15, row=quad*4+reg.
// ---------------------------------------------------------------------------
template <int DK, int DC, bool A_BF16>
__global__ __launch_bounds__(256) void k_gemm_mfma(const void* __restrict__ Av,
                                                   const ushort_t* __restrict__ Wt,
                                                   ushort_t* __restrict__ C, int n) {
    constexpr int BR = 64, BK = 32, NT = DC / 16, SA = 40;
    __shared__ __align__(16) ushort_t As[BR * SA];
    __shared__ __align__(16) ushort_t Ws[DC * SA];

    const int tid  = threadIdx.x;
    const int w    = tid >> 6;
    const int lane = tid & 63;
    const int m    = lane & 15;
    const int quad = lane >> 4;
    const int row0 = blockIdx.x * BR;

    floatx4 acc[NT];
#pragma unroll
    for (int t = 0; t < NT; ++t) acc[t] = (floatx4){0.f, 0.f, 0.f, 0.f};

    // A staging map: thread -> (row, k-offset of 8)
    const int ar = tid >> 2;          // 0..63
    const int ak = (tid & 3) * 8;     // 0,8,16,24
    int arr = row0 + ar; if (arr >= n) arr = n - 1;   // clamp; dup discarded at store

    for (int k0 = 0; k0 < DK; k0 += BK) {
        __syncthreads();   // previous iter's LDS reads done

        // --- stage A tile ---
        if constexpr (A_BF16) {
            const ushort_t* Ab = (const ushort_t*)Av + (size_t)arr * DK;
            ushort8 ap = *reinterpret_cast<const ushort8*>(Ab + k0 + ak);
            *reinterpret_cast<ushort8*>(&As[ar * SA + ak]) = ap;
        } else {
            const float* Ab = (const float*)Av + (size_t)arr * DK;
            float4 a0 = *reinterpret_cast<const float4*>(Ab + k0 + ak);
            float4 a1 = *reinterpret_cast<const float4*>(Ab + k0 + ak + 4);
            ushort8 ap = { f2bf(a0.x), f2bf(a0.y), f2bf(a0.z), f2bf(a0.w),
                           f2bf(a1.x), f2bf(a1.y), f2bf(a1.z), f2bf(a1.w) };
            *reinterpret_cast<ushort8*>(&As[ar * SA + ak]) = ap;
        }

        // --- stage W tile (bf16, pre-transposed) ---
        if constexpr (DC == 128) {
            int c = tid >> 1, koff = (tid & 1) * 16;
            ushort8 w0 = *reinterpret_cast<const ushort8*>(&Wt[(size_t)c * DK + k0 + koff]);
            ushort8 w1 = *reinterpret_cast<const ushort8*>(&Wt[(size_t)c * DK + k0 + koff + 8]);
            *reinterpret_cast<ushort8*>(&Ws[c * SA + koff])     = w0;
            *reinterpret_cast<ushort8*>(&Ws[c * SA + koff + 8]) = w1;
        } else {  // DC == 64
            int c = tid >> 2, koff = (tid & 3) * 8;
            ushort8 w0 = *reinterpret_cast<const ushort8*>(&Wt[(size_t)c * DK + k0 + koff]);
            *reinterpret_cast<ushort8*>(&Ws[c * SA + koff]) = w0;
        }
        __syncthreads();

        // --- MFMA ---
        bf16x8 a = *reinterpret_cast<bf16x8*>(&As[(w * 16 + m) * SA + quad * 8]);
#pragma unroll
        for (int t = 0; t < NT; ++t) {
            bf16x8 b = *reinterpret_cast<bf16x8*>(&Ws[(t * 16 + m) * SA + quad * 8]);
            acc[t] = __builtin_amdgcn_mfma_f32_16x16x32_bf16(a, b, acc[t], 0, 0, 0);
        }
    }

    // --- store bf16: D col = lane&15, row = quad*4 + i ---
#pragma unroll
    for (int t = 0; t < NT; ++t) {
#pragma unroll
        for (int i = 0; i < 4; ++i) {
            int r = row0 + w * 16 + quad * 4 + i;
            if (r < n) C[(size_t)r * DC + t * 16 + m] = f2bf(acc[t][i]);
        }
    }
}

// ---------------------------------------------------------------------------
// CSR SpMM over bf16 support, fp32 accumulate. One WAVE per row.
// D=128: lane covers 2 cols (one dword = 2 bf16 per gather).
// D=64:  lane covers 1 col (ushort gather; traffic is line-granular anyway).
// OUT_BF16 selects bf16 (intermediate h) vs fp32 (final out) stores.
// ---------------------------------------------------------------------------
template <int D, bool RELU, bool OUT_BF16>
__global__ __launch_bounds__(256) void k_spmm(const int* __restrict__ rp,
                                              const int2* __restrict__ ep,
                                              const ushort_t* __restrict__ sup,
                                              const float* __restrict__ bias,
                                              void* __restrict__ outv, int n) {
    const int w    = (blockIdx.x * 256 + threadIdx.x) >> 6;
    const int lane = threadIdx.x & 63;
    if (w >= n) return;
    const int s = rp[w], e = rp[w + 1];

    if constexpr (D == 128) {
        const int d = lane * 2;
        float accx = 0.f, accy = 0.f;
        int i = s;
        for (; i + 4 <= e; i += 4) {
            int2 r0 = ep[i], r1 = ep[i + 1], r2 = ep[i + 2], r3 = ep[i + 3];
            unsigned u0 = *reinterpret_cast<const unsigned*>(&sup[(size_t)r0.x * D + d]);
            unsigned u1 = *reinterpret_cast<const unsigned*>(&sup[(size_t)r1.x * D + d]);
            unsigned u2 = *reinterpret_cast<const unsigned*>(&sup[(size_t)r2.x * D + d]);
            unsigned u3 = *reinterpret_cast<const unsigned*>(&sup[(size_t)r3.x * D + d]);
            float w0 = __int_as_float(r0.y), w1 = __int_as_float(r1.y);
            float w2 = __int_as_float(r2.y), w3 = __int_as_float(r3.y);
            accx = fmaf(w0, __uint_as_float(u0 << 16), accx);
            accy = fmaf(w0, __uint_as_float(u0 & 0xFFFF0000u), accy);
            accx = fmaf(w1, __uint_as_float(u1 << 16), accx);
            accy = fmaf(w1, __uint_as_float(u1 & 0xFFFF0000u), accy);
            accx = fmaf(w2, __uint_as_float(u2 << 16), accx);
            accy = fmaf(w2, __uint_as_float(u2 & 0xFFFF0000u), accy);
            accx = fmaf(w3, __uint_as_float(u3 << 16), accx);
            accy = fmaf(w3, __uint_as_float(u3 & 0xFFFF0000u), accy);
        }
        for (; i < e; ++i) {
            int2 r = ep[i];
            unsigned u = *reinterpret_cast<const unsigned*>(&sup[(size_t)r.x * D + d]);
            float ww = __int_as_float(r.y);
            accx = fmaf(ww, __uint_as_float(u << 16), accx);
            accy = fmaf(ww, __uint_as_float(u & 0xFFFF0000u), accy);
        }
        accx += bias[d]; accy += bias[d + 1];
        if (RELU) { accx = fmaxf(accx, 0.f); accy = fmaxf(accy, 0.f); }
        if constexpr (OUT_BF16) {
            unsigned pk = (unsigned)f2bf(accx) | ((unsigned)f2bf(accy) << 16);
            *reinterpret_cast<unsigned*>((ushort_t*)outv + (size_t)w * D + d) = pk;
        } else {
            *reinterpret_cast<float2*>((float*)outv + (size_t)w * D + d) =
                make_float2(accx, accy);
        }
    } else {
        const int d = lane;
        float acc = 0.f;
        int i = s;
        for (; i + 4 <= e; i += 4) {
            int2 r0 = ep[i], r1 = ep[i + 1], r2 = ep[i + 2], r3 = ep[i + 3];
            float v0 = bf2f(sup[(size_t)r0.x * D + d]);
            float v1 = bf2f(sup[(size_t)r1.x * D + d]);
            float v2 = bf2f(sup[(size_t)r2.x * D + d]);
            float v3 = bf2f(sup[(size_t)r3.x * D + d]);
            acc = fmaf(__int_as_float(r0.y), v0, acc);
            acc = fmaf(__int_as_float(r1.y), v1, acc);
            acc = fmaf(__int_as_float(r2.y), v2, acc);
            acc = fmaf(__int_as_float(r3.y), v3, acc);
        }
        for (; i < e; ++i) {
            int2 r = ep[i];
            acc = fmaf(__int_as_float(r.y), bf2f(sup[(size_t)r.x * D + d]), acc);
        }
        acc += bias[d];
        if (RELU) acc = fmaxf(acc, 0.f);
        if constexpr (OUT_BF16)
            ((ushort_t*)outv)[(size_t)w * D + d] = f2bf(acc);
        else
            ((float*)outv)[(size_t)w * D + d] = acc;
    }
}

// ---------------------------------------------------------------------------

extern "C" void kernel_launch(void* const* d_in, const int* in_sizes, int n_in,
                              void* d_out, int out_size, void* d_ws, size_t ws_size,
                              hipStream_t stream) {
    const float* x  = (const float*)d_in[0];
    const int*   ei = (const int*)d_in[1];
    const float* ew = (const float*)d_in[2];
    const float* W1 = (const float*)d_in[3];
    const float* b1 = (const float*)d_in[4];
    const float* W2 = (const float*)d_in[5];
    const float* b2 = (const float*)d_in[6];
    float* out = (float*)d_out;

    const int n = in_sizes[0] / IN_DIM;  // 50000
    const int E = in_sizes[2];           // 1600000
    const int* rows = ei;
    const int* cols = ei + E;

    char* ws = (char*)d_ws;
    size_t off = 0;
    auto alloc = [&](size_t bytes) -> void* {
        off = (off + 255) & ~(size_t)255;
        void* p = ws + off;
        off += bytes;
        return p;
    };
    int2*     ep       = (int2*)alloc((size_t)E * sizeof(int2));
    int*      deg      = (int*)alloc((size_t)n * sizeof(int));
    int*      row_ptr  = (int*)alloc((size_t)(n + 1) * sizeof(int));
    int*      row_fill = (int*)alloc((size_t)n * sizeof(int));   // fallback only
    int*      bsum     = (int*)alloc(256 * sizeof(int));
    int*      bscan    = (int*)alloc(256 * sizeof(int));
    int*      bfill    = (int*)alloc(NBMAX * sizeof(int));
    ushort_t* Wt1      = (ushort_t*)alloc((size_t)IN_DIM * HID_DIM * sizeof(ushort_t));
    ushort_t* Wt2      = (ushort_t*)alloc((size_t)HID_DIM * OUT_DIM * sizeof(ushort_t));
    // sup1 region doubles as ept (bin temp); size for whichever is larger
    size_t sup1_bytes = (size_t)n * HID_DIM * sizeof(ushort_t);
    size_t ept_bytes  = (size_t)E * sizeof(int2);
    ushort_t* sup1     = (ushort_t*)alloc(sup1_bytes > ept_bytes ? sup1_bytes : ept_bytes);
    ushort_t* h        = (ushort_t*)alloc((size_t)n * HID_DIM * sizeof(ushort_t));
    ushort_t* sup2     = sup1;            // sup1 dead after spmm1
    int2*     ept      = (int2*)sup1;     // bin temp aliases sup1 (dead until gemm1)

    const int nb  = (n + SCAN_TILE - 1) / SCAN_TILE;
    const int nbk = (n + 127) / 128;
    const int gemm_b = (n + 63) / 64;

    // --- weight prep (independent of CSR) ---
    k_wcvt<<<(IN_DIM * HID_DIM + 255) / 256, 256, 0, stream>>>(W1, Wt1, IN_DIM, HID_DIM);
    k_wcvt<<<(HID_DIM * OUT_DIM + 255) / 256, 256, 0, stream>>>(W2, Wt2, HID_DIM, OUT_DIM);

    // --- CSR build ---
    k_zero<<<(n + 255) / 256, 256, 0, stream>>>(deg, n);
    k_hist<<<(E + 255) / 256, 256, 0, stream>>>(rows, deg, E);
    k_scan1<<<nb, 256, 0, stream>>>(deg, bsum, n);
    k_scan2<<<1, 256, 0, stream>>>(bsum, bscan, nb);
    k_scan3<<<nb, 256, 0, stream>>>(deg, bscan, row_ptr, n, E);

    if (n <= 65536) {
        k_binit<<<(nbk + 255) / 256, 256, 0, stream>>>(row_ptr, bfill, nbk);
        k_bin<<<(E + BIN_TILE - 1) / BIN_TILE, 256, 0, stream>>>(rows, cols, ew, bfill, ept, E, nbk);
        k_unbin<<<nbk, 256, 0, stream>>>(row_ptr, ept, ep, n);
    } else {
        k_fillinit<<<(n + 255) / 256, 256, 0, stream>>>(row_ptr, row_fill, n);
        k_scatter<<<(E + 255) / 256, 256, 0, stream>>>(rows, cols, ew, row_fill, ep, E);
    }

    // --- Layer 1 ---
    k_gemm_mfma<IN_DIM, HID_DIM, false><<<gemm_b, 256, 0, stream>>>(x, Wt1, sup1, n);
    k_spmm<HID_DIM, true, true><<<(n + 3) / 4, 256, 0, stream>>>(row_ptr, ep, sup1, b1, h, n);

    // --- Layer 2 ---
    k_gemm_mfma<HID_DIM, OUT_DIM, true><<<gemm_b, 256, 0, stream>>>(h, Wt2, sup2, n);
    k_spmm<OUT_DIM, false, false><<<(n + 3) / 4, 256, 0, stream>>>(row_ptr, ep, sup2, b2, out, n);
}

// Round 8
// 365.675 us; speedup vs baseline: 2.0453x; 1.1566x over previous
//
#include <hip/hip_runtime.h>

// Problem constants: N=50000, E=1.6M, dims 512 -> 128 -> 64
#define IN_DIM  512
#define HID_DIM 128
#define OUT_DIM 64

typedef unsigned short ushort_t;
typedef ushort_t ushort8 __attribute__((ext_vector_type(8)));
typedef __bf16  bf16x8  __attribute__((ext_vector_type(8)));
typedef float   floatx4 __attribute__((ext_vector_type(4)));

// fp32 -> bf16 round-to-nearest-even (bit trick; inputs are finite)
__device__ __forceinline__ ushort_t f2bf(float f) {
    union { float f; unsigned u; } v; v.f = f;
    unsigned r = v.u + 0x7FFFu + ((v.u >> 16) & 1u);
    return (ushort_t)(r >> 16);
}
__device__ __forceinline__ float bf2f(ushort_t u) {
    return __uint_as_float(((unsigned)u) << 16);
}

__global__ void k_zero(int* __restrict__ p, int n) {
    int i = blockIdx.x * blockDim.x + threadIdx.x;
    if (i < n) p[i] = 0;
}

// ---------------------------------------------------------------------------
// CSR build, bucket-level (128 rows/bucket):
//   bhist (LDS-privatized bucket histogram) -> bscan -> bin -> unbin
// Row-level row_ptr is derived inside k_unbin from each bucket's own edges.
// Requires n <= 65536 (col fits 16 bits, nbk <= 512 fits 9 bits).
// ---------------------------------------------------------------------------

#define BIN_TILE 4096
#define BH_TILE  8192
#define NBMAX    512

// LDS-privatized histogram of edge buckets (row >> 7).
__global__ __launch_bounds__(256) void k_bhist(const int* __restrict__ rows,
                                               int* __restrict__ bcnt, int E) {
    __shared__ int lc[NBMAX];
    const int t = threadIdx.x;
    lc[t] = 0; lc[t + 256] = 0;
    __syncthreads();
    const int base = blockIdx.x * BH_TILE;
#pragma unroll
    for (int j = 0; j < BH_TILE / 256; ++j) {
        int e = base + t + j * 256;
        if (e < E) atomicAdd(&lc[rows[e] >> 7], 1);
    }
    __syncthreads();
    if (lc[t])       atomicAdd(&bcnt[t], lc[t]);
    if (lc[t + 256]) atomicAdd(&bcnt[t + 256], lc[t + 256]);
}

// Exclusive scan of nbk (<=512) bucket counts -> bucket_base (+fill copy).
__global__ __launch_bounds__(256) void k_bscan(const int* __restrict__ bcnt,
                                               int* __restrict__ bucket_base,
                                               int* __restrict__ bucket_fill,
                                               int nbk, int E) {
    __shared__ int s[NBMAX];
    const int t = threadIdx.x;
    s[t]       = (t < nbk) ? bcnt[t] : 0;
    s[t + 256] = (t + 256 < nbk) ? bcnt[t + 256] : 0;
    __syncthreads();
    for (int d = 1; d < NBMAX; d <<= 1) {
        int v0 = (t >= d) ? s[t - d] : 0;
        int v1 = (t + 256 >= d) ? s[t + 256 - d] : 0;
        __syncthreads();
        s[t] += v0; s[t + 256] += v1;
        __syncthreads();
    }
#pragma unroll
    for (int l = 0; l < 2; ++l) {
        int i = t + l * 256;
        if (i < nbk) {
            int v = (i == 0) ? 0 : s[i - 1];
            bucket_base[i] = v;
            bucket_fill[i] = v;
        }
    }
    if (t == 0) bucket_base[nbk] = E;
}

// Phase A: bin edges into bucket regions of ept with LDS staging so global
// writes are coalesced runs. Record: .x = col | rowoff<<16 | bucket<<23, .y = w.
__global__ __launch_bounds__(256) void k_bin(const int* __restrict__ rows,
                                             const int* __restrict__ cols,
                                             const float* __restrict__ ew,
                                             int* __restrict__ bucket_fill,
                                             int2* __restrict__ ept, int E, int nbk) {
    __shared__ int cnt[NBMAX], inc[NBMAX], cnt2[NBMAX], gbase[NBMAX];
    __shared__ int2 stage[BIN_TILE];
    const int t = threadIdx.x;
    const int tile0 = blockIdx.x * BIN_TILE;

    cnt[t] = 0; cnt[t + 256] = 0; cnt2[t] = 0; cnt2[t + 256] = 0;
    __syncthreads();

    int px[16], pw[16];
    int nv = 0;
#pragma unroll
    for (int j = 0; j < 16; ++j) {
        int e = tile0 + t + j * 256;
        if (e < E) {
            int r = rows[e];
            int b = r >> 7;
            px[nv] = cols[e] | ((r & 127) << 16) | (b << 23);
            pw[nv] = __float_as_int(ew[e]);
            ++nv;
            atomicAdd(&cnt[b], 1);
        }
    }
    __syncthreads();

    inc[t] = cnt[t]; inc[t + 256] = cnt[t + 256];
    __syncthreads();
    for (int d = 1; d < NBMAX; d <<= 1) {
        int v0 = (t >= d) ? inc[t - d] : 0;
        int v1 = (t + 256 >= d) ? inc[t + 256 - d] : 0;
        __syncthreads();
        inc[t] += v0; inc[t + 256] += v1;
        __syncthreads();
    }

    if (t < nbk && cnt[t] > 0)             gbase[t]       = atomicAdd(&bucket_fill[t], cnt[t]);
    if (t + 256 < nbk && cnt[t + 256] > 0) gbase[t + 256] = atomicAdd(&bucket_fill[t + 256], cnt[t + 256]);

    for (int j = 0; j < nv; ++j) {
        int b = ((unsigned)px[j]) >> 23;
        int off = (b == 0) ? 0 : inc[b - 1];
        int r = atomicAdd(&cnt2[b], 1);
        stage[off + r] = make_int2(px[j], pw[j]);
    }
    __syncthreads();

    int total = inc[nbk - 1];
    for (int s = t; s < total; s += 256) {
        int2 rec = stage[s];
        int b = ((unsigned)rec.x) >> 23;
        int off = (b == 0) ? 0 : inc[b - 1];
        ept[gbase[b] + (s - off)] = rec;
    }
}

// Phase B: one block per bucket. Counts its 128 rows (LDS), scans them,
// WRITES row_ptr for the bucket, then scatters records to final CSR slots.
// All traffic confined to the bucket's contiguous span -> L2-local.
__global__ __launch_bounds__(256) void k_unbin(const int* __restrict__ bucket_base,
                                               const int2* __restrict__ ept,
                                               int2* __restrict__ ep,
                                               int* __restrict__ row_ptr,
                                               int n, int E, int nbk) {
    __shared__ int rcnt[128], sc[128], fill[128];
    const int b = blockIdx.x;
    const int t = threadIdx.x;
    const int r0 = b << 7;
    const int nrows = (n - r0 < 128) ? (n - r0) : 128;
    const int bstart = bucket_base[b];
    const int bend   = bucket_base[b + 1];

    if (t < 128) rcnt[t] = 0;
    __syncthreads();

    // pass 1: row-offset histogram (bucket span is L2-hot for pass 2)
    for (int e = bstart + t; e < bend; e += 256) {
        int ro = (ept[e].x >> 16) & 127;
        atomicAdd(&rcnt[ro], 1);
    }
    __syncthreads();

    // scan 128 counts (inclusive, threads 0..127)
    if (t < 128) sc[t] = rcnt[t];
    __syncthreads();
    for (int d = 1; d < 128; d <<= 1) {
        int v = (t >= d && t < 128) ? sc[t - d] : 0;
        __syncthreads();
        if (t < 128) sc[t] += v;
        __syncthreads();
    }
    if (t < 128) {
        int base = bstart + ((t == 0) ? 0 : sc[t - 1]);
        fill[t] = base;
        if (t < nrows) row_ptr[r0 + t] = base;
    }
    if (b == nbk - 1 && t == 0) row_ptr[n] = E;
    __syncthreads();

    // pass 2: scatter within the bucket's contiguous CSR span
    for (int e = bstart + t; e < bend; e += 256) {
        int2 rec = ept[e];
        int ro = (rec.x >> 16) & 127;
        int p = atomicAdd(&fill[ro], 1);
        ep[p] = make_int2(rec.x & 0xFFFF, rec.y);
    }
}

// --- fallback CSR build for n > 65536: hist -> 3-kernel scan -> scatter ----

__global__ void k_hist(const int* __restrict__ rows, int* __restrict__ deg, int E) {
    int i = blockIdx.x * blockDim.x + threadIdx.x;
    if (i < E) atomicAdd(&deg[rows[i]], 1);
}

#define SCAN_TILE 2048

__global__ __launch_bounds__(256) void k_scan1(const int* __restrict__ deg,
                                               int* __restrict__ bsum, int n) {
    __shared__ int s[256];
    const int tid = threadIdx.x;
    const int base = blockIdx.x * SCAN_TILE + tid * 8;
    int sum = 0;
#pragma unroll
    for (int i = 0; i < 8; ++i) { int idx = base + i; if (idx < n) sum += deg[idx]; }
    s[tid] = sum;
    __syncthreads();
#pragma unroll
    for (int off = 128; off > 0; off >>= 1) {
        if (tid < off) s[tid] += s[tid + off];
        __syncthreads();
    }
    if (tid == 0) bsum[blockIdx.x] = s[0];
}

__global__ __launch_bounds__(256) void k_scan2(const int* __restrict__ bsum,
                                               int* __restrict__ bscan, int nb) {
    __shared__ int s[256];
    const int tid = threadIdx.x;
    s[tid] = (tid < nb) ? bsum[tid] : 0;
    __syncthreads();
#pragma unroll
    for (int off = 1; off < 256; off <<= 1) {
        int v = (tid >= off) ? s[tid - off] : 0;
        __syncthreads();
        s[tid] += v;
        __syncthreads();
    }
    if (tid < nb) bscan[tid] = (tid == 0) ? 0 : s[tid - 1];
}

__global__ __launch_bounds__(256) void k_scan3(const int* __restrict__ deg,
                                               const int* __restrict__ bscan,
                                               int* __restrict__ row_ptr,
                                               int* __restrict__ row_fill,
                                               int n, int E) {
    __shared__ int s[256];
    const int tid = threadIdx.x;
    const int base = blockIdx.x * SCAN_TILE + tid * 8;
    int v[8];
#pragma unroll
    for (int i = 0; i < 8; ++i) { int idx = base + i; v[i] = (idx < n) ? deg[idx] : 0; }
    int sum = 0;
#pragma unroll
    for (int i = 0; i < 8; ++i) sum += v[i];
    s[tid] = sum;
    __syncthreads();
#pragma unroll
    for (int off = 1; off < 256; off <<= 1) {
        int t = (tid >= off) ? s[tid - off] : 0;
        __syncthreads();
        s[tid] += t;
        __syncthreads();
    }
    int run = bscan[blockIdx.x] + ((tid == 0) ? 0 : s[tid - 1]);
#pragma unroll
    for (int i = 0; i < 8; ++i) {
        int idx = base + i;
        if (idx < n) {
            row_ptr[idx]  = run;
            row_fill[idx] = run;
            run += v[i];
        }
    }
    if (blockIdx.x == 0 && tid == 0) row_ptr[n] = E;
}

__global__ void k_scatter(const int* __restrict__ rows, const int* __restrict__ cols,
                          const float* __restrict__ ew, int* __restrict__ row_fill,
                          int2* __restrict__ ep, int E) {
    int i = blockIdx.x * blockDim.x + threadIdx.x;
    if (i < E) {
        int r = rows[i];
        int p = atomicAdd(&row_fill[r], 1);
        ep[p] = make_int2(cols[i], __float_as_int(ew[i]));
    }
}

// ---------------------------------------------------------------------------
// Weight transpose + bf16 convert: W[DK x DC] fp32 -> Wt[DC x DK] bf16
// ---------------------------------------------------------------------------
__global__ void k_wcvt(const float* __restrict__ W, ushort_t* __restrict__ Wt,
                       int DKd, int DCd) {
    int i = blockIdx.x * blockDim.x + threadIdx.x;
    if (i < DKd * DCd) {
        int k = i / DCd, c = i % DCd;
        Wt[(size_t)c * DKd + k] = f2bf(W[i]);
    }
}

// ---------------------------------------------------------------------------
// MFMA bf16 GEMM: C[n x DC] (bf16) = A[n x DK] @ W[DK x DC], fp32 accumulate.
// ---------------------------------------------------------------------------
template <int DK, int DC, bool A_BF16>
__global__ __launch_bounds__(256) void k_gemm_mfma(const void* __restrict__ Av,
                                                   const ushort_t* __restrict__ Wt,
                                                   ushort_t* __restrict__ C, int n) {
    constexpr int BR = 64, BK = 32, NT = DC / 16, SA = 40;
    __shared__ __align__(16) ushort_t As[BR * SA];
    __shared__ __align__(16) ushort_t Ws[DC * SA];

    const int tid  = threadIdx.x;
    const int w    = tid >> 6;
    const int lane = tid & 63;
    const int m    = lane & 15;
    const int quad = lane >> 4;
    const int row0 = blockIdx.x * BR;

    floatx4 acc[NT];
#pragma unroll
    for (int t = 0; t < NT; ++t) acc[t] = (floatx4){0.f, 0.f, 0.f, 0.f};

    const int ar = tid >> 2;
    const int ak = (tid & 3) * 8;
    int arr = row0 + ar; if (arr >= n) arr = n - 1;

    for (int k0 = 0; k0 < DK; k0 += BK) {
        __syncthreads();

        if constexpr (A_BF16) {
            const ushort_t* Ab = (const ushort_t*)Av + (size_t)arr * DK;
            ushort8 ap = *reinterpret_cast<const ushort8*>(Ab + k0 + ak);
            *reinterpret_cast<ushort8*>(&As[ar * SA + ak]) = ap;
        } else {
            const float* Ab = (const float*)Av + (size_t)arr * DK;
            float4 a0 = *reinterpret_cast<const float4*>(Ab + k0 + ak);
            float4 a1 = *reinterpret_cast<const float4*>(Ab + k0 + ak + 4);
            ushort8 ap = { f2bf(a0.x), f2bf(a0.y), f2bf(a0.z), f2bf(a0.w),
                           f2bf(a1.x), f2bf(a1.y), f2bf(a1.z), f2bf(a1.w) };
            *reinterpret_cast<ushort8*>(&As[ar * SA + ak]) = ap;
        }

        if constexpr (DC == 128) {
            int c = tid >> 1, koff = (tid & 1) * 16;
            ushort8 w0 = *reinterpret_cast<const ushort8*>(&Wt[(size_t)c * DK + k0 + koff]);
            ushort8 w1 = *reinterpret_cast<const ushort8*>(&Wt[(size_t)c * DK + k0 + koff + 8]);
            *reinterpret_cast<ushort8*>(&Ws[c * SA + koff])     = w0;
            *reinterpret_cast<ushort8*>(&Ws[c * SA + koff + 8]) = w1;
        } else {
            int c = tid >> 2, koff = (tid & 3) * 8;
            ushort8 w0 = *reinterpret_cast<const ushort8*>(&Wt[(size_t)c * DK + k0 + koff]);
            *reinterpret_cast<ushort8*>(&Ws[c * SA + koff]) = w0;
        }
        __syncthreads();

        bf16x8 a = *reinterpret_cast<bf16x8*>(&As[(w * 16 + m) * SA + quad * 8]);
#pragma unroll
        for (int t = 0; t < NT; ++t) {
            bf16x8 b = *reinterpret_cast<bf16x8*>(&Ws[(t * 16 + m) * SA + quad * 8]);
            acc[t] = __builtin_amdgcn_mfma_f32_16x16x32_bf16(a, b, acc[t], 0, 0, 0);
        }
    }

#pragma unroll
    for (int t = 0; t < NT; ++t) {
#pragma unroll
        for (int i = 0; i < 4; ++i) {
            int r = row0 + w * 16 + quad * 4 + i;
            if (r < n) C[(size_t)r * DC + t * 16 + m] = f2bf(acc[t][i]);
        }
    }
}

// ---------------------------------------------------------------------------
// CSR SpMM over bf16 support, fp32 accumulate. One WAVE per row.
// ---------------------------------------------------------------------------
template <int D, bool RELU, bool OUT_BF16>
__global__ __launch_bounds__(256) void k_spmm(const int* __restrict__ rp,
                                              const int2* __restrict__ ep,
                                              const ushort_t* __restrict__ sup,
                                              const float* __restrict__ bias,
                                              void* __restrict__ outv, int n) {
    const int w    = (blockIdx.x * 256 + threadIdx.x) >> 6;
    const int lane = threadIdx.x & 63;
    if (w >= n) return;
    const int s = rp[w], e = rp[w + 1];

    if constexpr (D == 128) {
        const int d = lane * 2;
        float accx = 0.f, accy = 0.f;
        int i = s;
        for (; i + 4 <= e; i += 4) {
            int2 r0 = ep[i], r1 = ep[i + 1], r2 = ep[i + 2], r3 = ep[i + 3];
            unsigned u0 = *reinterpret_cast<const unsigned*>(&sup[(size_t)r0.x * D + d]);
            unsigned u1 = *reinterpret_cast<const unsigned*>(&sup[(size_t)r1.x * D + d]);
            unsigned u2 = *reinterpret_cast<const unsigned*>(&sup[(size_t)r2.x * D + d]);
            unsigned u3 = *reinterpret_cast<const unsigned*>(&sup[(size_t)r3.x * D + d]);
            float w0 = __int_as_float(r0.y), w1 = __int_as_float(r1.y);
            float w2 = __int_as_float(r2.y), w3 = __int_as_float(r3.y);
            accx = fmaf(w0, __uint_as_float(u0 << 16), accx);
            accy = fmaf(w0, __uint_as_float(u0 & 0xFFFF0000u), accy);
            accx = fmaf(w1, __uint_as_float(u1 << 16), accx);
            accy = fmaf(w1, __uint_as_float(u1 & 0xFFFF0000u), accy);
            accx = fmaf(w2, __uint_as_float(u2 << 16), accx);
            accy = fmaf(w2, __uint_as_float(u2 & 0xFFFF0000u), accy);
            accx = fmaf(w3, __uint_as_float(u3 << 16), accx);
            accy = fmaf(w3, __uint_as_float(u3 & 0xFFFF0000u), accy);
        }
        for (; i < e; ++i) {
            int2 r = ep[i];
            unsigned u = *reinterpret_cast<const unsigned*>(&sup[(size_t)r.x * D + d]);
            float ww = __int_as_float(r.y);
            accx = fmaf(ww, __uint_as_float(u << 16), accx);
            accy = fmaf(ww, __uint_as_float(u & 0xFFFF0000u), accy);
        }
        accx += bias[d]; accy += bias[d + 1];
        if (RELU) { accx = fmaxf(accx, 0.f); accy = fmaxf(accy, 0.f); }
        if constexpr (OUT_BF16) {
            unsigned pk = (unsigned)f2bf(accx) | ((unsigned)f2bf(accy) << 16);
            *reinterpret_cast<unsigned*>((ushort_t*)outv + (size_t)w * D + d) = pk;
        } else {
            *reinterpret_cast<float2*>((float*)outv + (size_t)w * D + d) =
                make_float2(accx, accy);
        }
    } else {
        const int d = lane;
        float acc = 0.f;
        int i = s;
        for (; i + 4 <= e; i += 4) {
            int2 r0 = ep[i], r1 = ep[i + 1], r2 = ep[i + 2], r3 = ep[i + 3];
            float v0 = bf2f(sup[(size_t)r0.x * D + d]);
            float v1 = bf2f(sup[(size_t)r1.x * D + d]);
            float v2 = bf2f(sup[(size_t)r2.x * D + d]);
            float v3 = bf2f(sup[(size_t)r3.x * D + d]);
            acc = fmaf(__int_as_float(r0.y), v0, acc);
            acc = fmaf(__int_as_float(r1.y), v1, acc);
            acc = fmaf(__int_as_float(r2.y), v2, acc);
            acc = fmaf(__int_as_float(r3.y), v3, acc);
        }
        for (; i < e; ++i) {
            int2 r = ep[i];
            acc = fmaf(__int_as_float(r.y), bf2f(sup[(size_t)r.x * D + d]), acc);
        }
        acc += bias[d];
        if (RELU) acc = fmaxf(acc, 0.f);
        if constexpr (OUT_BF16)
            ((ushort_t*)outv)[(size_t)w * D + d] = f2bf(acc);
        else
            ((float*)outv)[(size_t)w * D + d] = acc;
    }
}

// ---------------------------------------------------------------------------

extern "C" void kernel_launch(void* const* d_in, const int* in_sizes, int n_in,
                              void* d_out, int out_size, void* d_ws, size_t ws_size,
                              hipStream_t stream) {
    const float* x  = (const float*)d_in[0];
    const int*   ei = (const int*)d_in[1];
    const float* ew = (const float*)d_in[2];
    const float* W1 = (const float*)d_in[3];
    const float* b1 = (const float*)d_in[4];
    const float* W2 = (const float*)d_in[5];
    const float* b2 = (const float*)d_in[6];
    float* out = (float*)d_out;

    const int n = in_sizes[0] / IN_DIM;  // 50000
    const int E = in_sizes[2];           // 1600000
    const int* rows = ei;
    const int* cols = ei + E;

    char* ws = (char*)d_ws;
    size_t off = 0;
    auto alloc = [&](size_t bytes) -> void* {
        off = (off + 255) & ~(size_t)255;
        void* p = ws + off;
        off += bytes;
        return p;
    };
    int2*     ep       = (int2*)alloc((size_t)E * sizeof(int2));
    int*      row_ptr  = (int*)alloc((size_t)(n + 1) * sizeof(int));
    int*      bcnt     = (int*)alloc(NBMAX * sizeof(int));
    int*      bbase    = (int*)alloc((NBMAX + 1) * sizeof(int));
    int*      bfill    = (int*)alloc(NBMAX * sizeof(int));
    ushort_t* Wt1      = (ushort_t*)alloc((size_t)IN_DIM * HID_DIM * sizeof(ushort_t));
    ushort_t* Wt2      = (ushort_t*)alloc((size_t)HID_DIM * OUT_DIM * sizeof(ushort_t));
    // sup1 region doubles as ept (bin temp); size for whichever is larger
    size_t sup1_bytes = (size_t)n * HID_DIM * sizeof(ushort_t);
    size_t ept_bytes  = (size_t)E * sizeof(int2);
    ushort_t* sup1     = (ushort_t*)alloc(sup1_bytes > ept_bytes ? sup1_bytes : ept_bytes);
    ushort_t* h        = (ushort_t*)alloc((size_t)n * HID_DIM * sizeof(ushort_t));
    ushort_t* sup2     = sup1;            // sup1 dead after spmm1
    int2*     ept      = (int2*)sup1;     // bin temp aliases sup1 (dead until gemm1)
    // fallback-path scratch (n > 65536)
    int*      deg      = nullptr;
    int*      row_fill = nullptr;
    int*      bsum     = nullptr;
    int*      bscan    = nullptr;

    const int nbk = (n + 127) / 128;
    const int gemm_b = (n + 63) / 64;

    // --- weight prep (independent of CSR) ---
    k_wcvt<<<(IN_DIM * HID_DIM + 255) / 256, 256, 0, stream>>>(W1, Wt1, IN_DIM, HID_DIM);
    k_wcvt<<<(HID_DIM * OUT_DIM + 255) / 256, 256, 0, stream>>>(W2, Wt2, HID_DIM, OUT_DIM);

    if (n <= 65536) {
        // --- CSR build, bucket-level (no row-level histogram) ---
        k_zero<<<(NBMAX + 255) / 256, 256, 0, stream>>>(bcnt, NBMAX);
        k_bhist<<<(E + BH_TILE - 1) / BH_TILE, 256, 0, stream>>>(rows, bcnt, E);
        k_bscan<<<1, 256, 0, stream>>>(bcnt, bbase, bfill, nbk, E);
        k_bin<<<(E + BIN_TILE - 1) / BIN_TILE, 256, 0, stream>>>(rows, cols, ew, bfill, ept, E, nbk);
        k_unbin<<<nbk, 256, 0, stream>>>(bbase, ept, ep, row_ptr, n, E, nbk);
    } else {
        // --- fallback: row-level hist -> scan -> direct scatter ---
        deg      = (int*)alloc((size_t)n * sizeof(int));
        row_fill = (int*)alloc((size_t)n * sizeof(int));
        bsum     = (int*)alloc(256 * sizeof(int));
        bscan    = (int*)alloc(256 * sizeof(int));
        const int nb = (n + SCAN_TILE - 1) / SCAN_TILE;
        k_zero<<<(n + 255) / 256, 256, 0, stream>>>(deg, n);
        k_hist<<<(E + 255) / 256, 256, 0, stream>>>(rows, deg, E);
        k_scan1<<<nb, 256, 0, stream>>>(deg, bsum, n);
        k_scan2<<<1, 256, 0, stream>>>(bsum, bscan, nb);
        k_scan3<<<nb, 256, 0, stream>>>(deg, bscan, row_ptr, row_fill, n, E);
        k_scatter<<<(E + 255) / 256, 256, 0, stream>>>(rows, cols, ew, row_fill, ep, E);
    }

    // --- Layer 1 ---
    k_gemm_mfma<IN_DIM, HID_DIM, false><<<gemm_b, 256, 0, stream>>>(x, Wt1, sup1, n);
    k_spmm<HID_DIM, true, true><<<(n + 3) / 4, 256, 0, stream>>>(row_ptr, ep, sup1, b1, h, n);

    // --- Layer 2 ---
    k_gemm_mfma<HID_DIM, OUT_DIM, true><<<gemm_b, 256, 0, stream>>>(h, Wt2, sup2, n);
    k_spmm<OUT_DIM, false, false><<<(n + 3) / 4, 256, 0, stream>>>(row_ptr, ep, sup2, b2, out, n);
}

// Round 9
// 352.981 us; speedup vs baseline: 2.1189x; 1.0360x over previous
//
#include <hip/hip_runtime.h>
#include <hip/hip_fp8.h>

// Problem constants: N=50000, E=1.6M, dims 512 -> 128 -> 64
#define IN_DIM  512
#define HID_DIM 128
#define OUT_DIM 64

typedef unsigned short ushort_t;
typedef ushort_t ushort8 __attribute__((ext_vector_type(8)));
typedef __bf16  bf16x8  __attribute__((ext_vector_type(8)));
typedef float   floatx4 __attribute__((ext_vector_type(4)));

// fp32 -> bf16 round-to-nearest-even (bit trick; inputs are finite)
__device__ __forceinline__ ushort_t f2bf(float f) {
    union { float f; unsigned u; } v; v.f = f;
    unsigned r = v.u + 0x7FFFu + ((v.u >> 16) & 1u);
    return (ushort_t)(r >> 16);
}
__device__ __forceinline__ float bf2f(ushort_t u) {
    return __uint_as_float(((unsigned)u) << 16);
}
// fp32 <-> fp8 e4m3 (OCP fn) via HIP type (HW v_cvt on gfx950)
__device__ __forceinline__ unsigned char f2fp8(float f) {
    __hip_fp8_e4m3 t(f); return (unsigned char)t.__x;
}
__device__ __forceinline__ float fp82f(unsigned char b) {
    __hip_fp8_e4m3 t; t.__x = (__hip_fp8_storage_t)b; return (float)t;
}

__global__ void k_zero(int* __restrict__ p, int n) {
    int i = blockIdx.x * blockDim.x + threadIdx.x;
    if (i < n) p[i] = 0;
}

// ---------------------------------------------------------------------------
// CSR build, bucket-level (128 rows/bucket):
//   bhist (LDS-privatized bucket histogram) -> bscan -> bin -> unbin
// Requires n <= 65536 (col fits 16 bits, nbk <= 512 fits 9 bits).
// ---------------------------------------------------------------------------

#define BIN_TILE 4096
#define BH_TILE  8192
#define NBMAX    512

__global__ __launch_bounds__(256) void k_bhist(const int* __restrict__ rows,
                                               int* __restrict__ bcnt, int E) {
    __shared__ int lc[NBMAX];
    const int t = threadIdx.x;
    lc[t] = 0; lc[t + 256] = 0;
    __syncthreads();
    const int base = blockIdx.x * BH_TILE;
#pragma unroll
    for (int j = 0; j < BH_TILE / 256; ++j) {
        int e = base + t + j * 256;
        if (e < E) atomicAdd(&lc[rows[e] >> 7], 1);
    }
    __syncthreads();
    if (lc[t])       atomicAdd(&bcnt[t], lc[t]);
    if (lc[t + 256]) atomicAdd(&bcnt[t + 256], lc[t + 256]);
}

__global__ __launch_bounds__(256) void k_bscan(const int* __restrict__ bcnt,
                                               int* __restrict__ bucket_base,
                                               int* __restrict__ bucket_fill,
                                               int nbk, int E) {
    __shared__ int s[NBMAX];
    const int t = threadIdx.x;
    s[t]       = (t < nbk) ? bcnt[t] : 0;
    s[t + 256] = (t + 256 < nbk) ? bcnt[t + 256] : 0;
    __syncthreads();
    for (int d = 1; d < NBMAX; d <<= 1) {
        int v0 = (t >= d) ? s[t - d] : 0;
        int v1 = (t + 256 >= d) ? s[t + 256 - d] : 0;
        __syncthreads();
        s[t] += v0; s[t + 256] += v1;
        __syncthreads();
    }
#pragma unroll
    for (int l = 0; l < 2; ++l) {
        int i = t + l * 256;
        if (i < nbk) {
            int v = (i == 0) ? 0 : s[i - 1];
            bucket_base[i] = v;
            bucket_fill[i] = v;
        }
    }
    if (t == 0) bucket_base[nbk] = E;
}

// Phase A: bin edges into bucket regions of ept with LDS staging.
// Record: .x = col | rowoff<<16 | bucket<<23, .y = weight bits.
__global__ __launch_bounds__(256) void k_bin(const int* __restrict__ rows,
                                             const int* __restrict__ cols,
                                             const float* __restrict__ ew,
                                             int* __restrict__ bucket_fill,
                                             int2* __restrict__ ept, int E, int nbk) {
    __shared__ int cnt[NBMAX], inc[NBMAX], cnt2[NBMAX], gbase[NBMAX];
    __shared__ int2 stage[BIN_TILE];
    const int t = threadIdx.x;
    const int tile0 = blockIdx.x * BIN_TILE;

    cnt[t] = 0; cnt[t + 256] = 0; cnt2[t] = 0; cnt2[t + 256] = 0;
    __syncthreads();

    int px[16], pw[16];
    int nv = 0;
#pragma unroll
    for (int j = 0; j < 16; ++j) {
        int e = tile0 + t + j * 256;
        if (e < E) {
            int r = rows[e];
            int b = r >> 7;
            px[nv] = cols[e] | ((r & 127) << 16) | (b << 23);
            pw[nv] = __float_as_int(ew[e]);
            ++nv;
            atomicAdd(&cnt[b], 1);
        }
    }
    __syncthreads();

    inc[t] = cnt[t]; inc[t + 256] = cnt[t + 256];
    __syncthreads();
    for (int d = 1; d < NBMAX; d <<= 1) {
        int v0 = (t >= d) ? inc[t - d] : 0;
        int v1 = (t + 256 >= d) ? inc[t + 256 - d] : 0;
        __syncthreads();
        inc[t] += v0; inc[t + 256] += v1;
        __syncthreads();
    }

    if (t < nbk && cnt[t] > 0)             gbase[t]       = atomicAdd(&bucket_fill[t], cnt[t]);
    if (t + 256 < nbk && cnt[t + 256] > 0) gbase[t + 256] = atomicAdd(&bucket_fill[t + 256], cnt[t + 256]);

    for (int j = 0; j < nv; ++j) {
        int b = ((unsigned)px[j]) >> 23;
        int off = (b == 0) ? 0 : inc[b - 1];
        int r = atomicAdd(&cnt2[b], 1);
        stage[off + r] = make_int2(px[j], pw[j]);
    }
    __syncthreads();

    int total = inc[nbk - 1];
    for (int s = t; s < total; s += 256) {
        int2 rec = stage[s];
        int b = ((unsigned)rec.x) >> 23;
        int off = (b == 0) ? 0 : inc[b - 1];
        ept[gbase[b] + (s - off)] = rec;
    }
}

// Phase B: one block per bucket; derives row_ptr for its 128 rows and
// scatters records to final CSR slots (all traffic L2-local to the bucket).
__global__ __launch_bounds__(256) void k_unbin(const int* __restrict__ bucket_base,
                                               const int2* __restrict__ ept,
                                               int2* __restrict__ ep,
                                               int* __restrict__ row_ptr,
                                               int n, int E, int nbk) {
    __shared__ int rcnt[128], sc[128], fill[128];
    const int b = blockIdx.x;
    const int t = threadIdx.x;
    const int r0 = b << 7;
    const int nrows = (n - r0 < 128) ? (n - r0) : 128;
    const int bstart = bucket_base[b];
    const int bend   = bucket_base[b + 1];

    if (t < 128) rcnt[t] = 0;
    __syncthreads();

    for (int e = bstart + t; e < bend; e += 256) {
        int ro = (ept[e].x >> 16) & 127;
        atomicAdd(&rcnt[ro], 1);
    }
    __syncthreads();

    if (t < 128) sc[t] = rcnt[t];
    __syncthreads();
    for (int d = 1; d < 128; d <<= 1) {
        int v = (t >= d && t < 128) ? sc[t - d] : 0;
        __syncthreads();
        if (t < 128) sc[t] += v;
        __syncthreads();
    }
    if (t < 128) {
        int base = bstart + ((t == 0) ? 0 : sc[t - 1]);
        fill[t] = base;
        if (t < nrows) row_ptr[r0 + t] = base;
    }
    if (b == nbk - 1 && t == 0) row_ptr[n] = E;
    __syncthreads();

    for (int e = bstart + t; e < bend; e += 256) {
        int2 rec = ept[e];
        int ro = (rec.x >> 16) & 127;
        int p = atomicAdd(&fill[ro], 1);
        ep[p] = make_int2(rec.x & 0xFFFF, rec.y);
    }
}

// --- fallback CSR build for n > 65536: hist -> 3-kernel scan -> scatter ----

__global__ void k_hist(const int* __restrict__ rows, int* __restrict__ deg, int E) {
    int i = blockIdx.x * blockDim.x + threadIdx.x;
    if (i < E) atomicAdd(&deg[rows[i]], 1);
}

#define SCAN_TILE 2048

__global__ __launch_bounds__(256) void k_scan1(const int* __restrict__ deg,
                                               int* __restrict__ bsum, int n) {
    __shared__ int s[256];
    const int tid = threadIdx.x;
    const int base = blockIdx.x * SCAN_TILE + tid * 8;
    int sum = 0;
#pragma unroll
    for (int i = 0; i < 8; ++i) { int idx = base + i; if (idx < n) sum += deg[idx]; }
    s[tid] = sum;
    __syncthreads();
#pragma unroll
    for (int off = 128; off > 0; off >>= 1) {
        if (tid < off) s[tid] += s[tid + off];
        __syncthreads();
    }
    if (tid == 0) bsum[blockIdx.x] = s[0];
}

__global__ __launch_bounds__(256) void k_scan2(const int* __restrict__ bsum,
                                               int* __restrict__ bscan, int nb) {
    __shared__ int s[256];
    const int tid = threadIdx.x;
    s[tid] = (tid < nb) ? bsum[tid] : 0;
    __syncthreads();
#pragma unroll
    for (int off = 1; off < 256; off <<= 1) {
        int v = (tid >= off) ? s[tid - off] : 0;
        __syncthreads();
        s[tid] += v;
        __syncthreads();
    }
    if (tid < nb) bscan[tid] = (tid == 0) ? 0 : s[tid - 1];
}

__global__ __launch_bounds__(256) void k_scan3(const int* __restrict__ deg,
                                               const int* __restrict__ bscan,
                                               int* __restrict__ row_ptr,
                                               int* __restrict__ row_fill,
                                               int n, int E) {
    __shared__ int s[256];
    const int tid = threadIdx.x;
    const int base = blockIdx.x * SCAN_TILE + tid * 8;
    int v[8];
#pragma unroll
    for (int i = 0; i < 8; ++i) { int idx = base + i; v[i] = (idx < n) ? deg[idx] : 0; }
    int sum = 0;
#pragma unroll
    for (int i = 0; i < 8; ++i) sum += v[i];
    s[tid] = sum;
    __syncthreads();
#pragma unroll
    for (int off = 1; off < 256; off <<= 1) {
        int t = (tid >= off) ? s[tid - off] : 0;
        __syncthreads();
        s[tid] += t;
        __syncthreads();
    }
    int run = bscan[blockIdx.x] + ((tid == 0) ? 0 : s[tid - 1]);
#pragma unroll
    for (int i = 0; i < 8; ++i) {
        int idx = base + i;
        if (idx < n) {
            row_ptr[idx]  = run;
            row_fill[idx] = run;
            run += v[i];
        }
    }
    if (blockIdx.x == 0 && tid == 0) row_ptr[n] = E;
}

__global__ void k_scatter(const int* __restrict__ rows, const int* __restrict__ cols,
                          const float* __restrict__ ew, int* __restrict__ row_fill,
                          int2* __restrict__ ep, int E) {
    int i = blockIdx.x * blockDim.x + threadIdx.x;
    if (i < E) {
        int r = rows[i];
        int p = atomicAdd(&row_fill[r], 1);
        ep[p] = make_int2(cols[i], __float_as_int(ew[i]));
    }
}

// ---------------------------------------------------------------------------
// Merged weight transpose + bf16 convert for W1 and W2 (one launch).
// ---------------------------------------------------------------------------
__global__ void k_wcvt2(const float* __restrict__ W1, ushort_t* __restrict__ Wt1,
                        const float* __restrict__ W2, ushort_t* __restrict__ Wt2) {
    int i = blockIdx.x * blockDim.x + threadIdx.x;
    if (i < IN_DIM * HID_DIM) {
        int k = i / HID_DIM, c = i % HID_DIM;
        Wt1[(size_t)c * IN_DIM + k] = f2bf(W1[i]);
    } else {
        int j = i - IN_DIM * HID_DIM;
        if (j < HID_DIM * OUT_DIM) {
            int k = j / OUT_DIM, c = j % OUT_DIM;
            Wt2[(size_t)c * HID_DIM + k] = f2bf(W2[j]);
        }
    }
}

// ---------------------------------------------------------------------------
// MFMA bf16 GEMM: C[n x DC] = A[n x DK] @ W[DK x DC], fp32 accumulate.
// OUT_FP8: store e4m3 (sup1, gathered by spmm1); else store bf16.
// ---------------------------------------------------------------------------
template <int DK, int DC, bool A_BF16, bool OUT_FP8>
__global__ __launch_bounds__(256) void k_gemm_mfma(const void* __restrict__ Av,
                                                   const ushort_t* __restrict__ Wt,
                                                   void* __restrict__ Cv, int n) {
    constexpr int BR = 64, BK = 32, NT = DC / 16, SA = 40;
    __shared__ __align__(16) ushort_t As[BR * SA];
    __shared__ __align__(16) ushort_t Ws[DC * SA];

    const int tid  = threadIdx.x;
    const int w    = tid >> 6;
    const int lane = tid & 63;
    const int m    = lane & 15;
    const int quad = lane >> 4;
    const int row0 = blockIdx.x * BR;

    floatx4 acc[NT];
#pragma unroll
    for (int t = 0; t < NT; ++t) acc[t] = (floatx4){0.f, 0.f, 0.f, 0.f};

    const int ar = tid >> 2;
    const int ak = (tid & 3) * 8;
    int arr = row0 + ar; if (arr >= n) arr = n - 1;

    for (int k0 = 0; k0 < DK; k0 += BK) {
        __syncthreads();

        if constexpr (A_BF16) {
            const ushort_t* Ab = (const ushort_t*)Av + (size_t)arr * DK;
            ushort8 ap = *reinterpret_cast<const ushort8*>(Ab + k0 + ak);
            *reinterpret_cast<ushort8*>(&As[ar * SA + ak]) = ap;
        } else {
            const float* Ab = (const float*)Av + (size_t)arr * DK;
            float4 a0 = *reinterpret_cast<const float4*>(Ab + k0 + ak);
            float4 a1 = *reinterpret_cast<const float4*>(Ab + k0 + ak + 4);
            ushort8 ap = { f2bf(a0.x), f2bf(a0.y), f2bf(a0.z), f2bf(a0.w),
                           f2bf(a1.x), f2bf(a1.y), f2bf(a1.z), f2bf(a1.w) };
            *reinterpret_cast<ushort8*>(&As[ar * SA + ak]) = ap;
        }

        if constexpr (DC == 128) {
            int c = tid >> 1, koff = (tid & 1) * 16;
            ushort8 w0 = *reinterpret_cast<const ushort8*>(&Wt[(size_t)c * DK + k0 + koff]);
            ushort8 w1 = *reinterpret_cast<const ushort8*>(&Wt[(size_t)c * DK + k0 + koff + 8]);
            *reinterpret_cast<ushort8*>(&Ws[c * SA + koff])     = w0;
            *reinterpret_cast<ushort8*>(&Ws[c * SA + koff + 8]) = w1;
        } else {
            int c = tid >> 2, koff = (tid & 3) * 8;
            ushort8 w0 = *reinterpret_cast<const ushort8*>(&Wt[(size_t)c * DK + k0 + koff]);
            *reinterpret_cast<ushort8*>(&Ws[c * SA + koff]) = w0;
        }
        __syncthreads();

        bf16x8 a = *reinterpret_cast<bf16x8*>(&As[(w * 16 + m) * SA + quad * 8]);
#pragma unroll
        for (int t = 0; t < NT; ++t) {
            bf16x8 b = *reinterpret_cast<bf16x8*>(&Ws[(t * 16 + m) * SA + quad * 8]);
            acc[t] = __builtin_amdgcn_mfma_f32_16x16x32_bf16(a, b, acc[t], 0, 0, 0);
        }
    }

#pragma unroll
    for (int t = 0; t < NT; ++t) {
#pragma unroll
        for (int i = 0; i < 4; ++i) {
            int r = row0 + w * 16 + quad * 4 + i;
            if (r < n) {
                if constexpr (OUT_FP8)
                    ((unsigned char*)Cv)[(size_t)r * DC + t * 16 + m] = f2fp8(acc[t][i]);
                else
                    ((ushort_t*)Cv)[(size_t)r * DC + t * 16 + m] = f2bf(acc[t][i]);
            }
        }
    }
}

// ---------------------------------------------------------------------------
// CSR SpMM, one WAVE per row, fp32 accumulate, 8-edge unroll.
// SUP_FP8: sup is e4m3 (D=128: lane loads 2 bytes); else bf16.
// OUT_BF16 selects bf16 (intermediate h) vs fp32 (final out) stores.
// ---------------------------------------------------------------------------
template <int D, bool RELU, bool OUT_BF16, bool SUP_FP8>
__global__ __launch_bounds__(256) void k_spmm(const int* __restrict__ rp,
                                              const int2* __restrict__ ep,
                                              const void* __restrict__ supv,
                                              const float* __restrict__ bias,
                                              void* __restrict__ outv, int n) {
    const int w    = (blockIdx.x * 256 + threadIdx.x) >> 6;
    const int lane = threadIdx.x & 63;
    if (w >= n) return;
    const int s = rp[w], e = rp[w + 1];

    if constexpr (D == 128) {
        const int d = lane * 2;
        float accx = 0.f, accy = 0.f;
        int i = s;
        for (; i + 8 <= e; i += 8) {
            int2 r[8];
#pragma unroll
            for (int j = 0; j < 8; ++j) r[j] = ep[i + j];
            if constexpr (SUP_FP8) {
                const unsigned char* sup = (const unsigned char*)supv;
                unsigned short u[8];
#pragma unroll
                for (int j = 0; j < 8; ++j)
                    u[j] = *reinterpret_cast<const unsigned short*>(&sup[(size_t)r[j].x * D + d]);
#pragma unroll
                for (int j = 0; j < 8; ++j) {
                    float ww = __int_as_float(r[j].y);
                    accx = fmaf(ww, fp82f((unsigned char)(u[j] & 255)), accx);
                    accy = fmaf(ww, fp82f((unsigned char)(u[j] >> 8)), accy);
                }
            } else {
                const ushort_t* sup = (const ushort_t*)supv;
                unsigned u[8];
#pragma unroll
                for (int j = 0; j < 8; ++j)
                    u[j] = *reinterpret_cast<const unsigned*>(&sup[(size_t)r[j].x * D + d]);
#pragma unroll
                for (int j = 0; j < 8; ++j) {
                    float ww = __int_as_float(r[j].y);
                    accx = fmaf(ww, __uint_as_float(u[j] << 16), accx);
                    accy = fmaf(ww, __uint_as_float(u[j] & 0xFFFF0000u), accy);
                }
            }
        }
        for (; i < e; ++i) {
            int2 r = ep[i];
            float ww = __int_as_float(r.y);
            if constexpr (SUP_FP8) {
                const unsigned char* sup = (const unsigned char*)supv;
                unsigned short u = *reinterpret_cast<const unsigned short*>(&sup[(size_t)r.x * D + d]);
                accx = fmaf(ww, fp82f((unsigned char)(u & 255)), accx);
                accy = fmaf(ww, fp82f((unsigned char)(u >> 8)), accy);
            } else {
                const ushort_t* sup = (const ushort_t*)supv;
                unsigned u = *reinterpret_cast<const unsigned*>(&sup[(size_t)r.x * D + d]);
                accx = fmaf(ww, __uint_as_float(u << 16), accx);
                accy = fmaf(ww, __uint_as_float(u & 0xFFFF0000u), accy);
            }
        }
        accx += bias[d]; accy += bias[d + 1];
        if (RELU) { accx = fmaxf(accx, 0.f); accy = fmaxf(accy, 0.f); }
        if constexpr (OUT_BF16) {
            unsigned pk = (unsigned)f2bf(accx) | ((unsigned)f2bf(accy) << 16);
            *reinterpret_cast<unsigned*>((ushort_t*)outv + (size_t)w * D + d) = pk;
        } else {
            *reinterpret_cast<float2*>((float*)outv + (size_t)w * D + d) =
                make_float2(accx, accy);
        }
    } else {
        const int d = lane;
        const ushort_t* sup = (const ushort_t*)supv;   // D=64 path: bf16 sup
        float acc = 0.f;
        int i = s;
        for (; i + 8 <= e; i += 8) {
            int2 r[8];
#pragma unroll
            for (int j = 0; j < 8; ++j) r[j] = ep[i + j];
            ushort_t u[8];
#pragma unroll
            for (int j = 0; j < 8; ++j) u[j] = sup[(size_t)r[j].x * D + d];
#pragma unroll
            for (int j = 0; j < 8; ++j)
                acc = fmaf(__int_as_float(r[j].y), bf2f(u[j]), acc);
        }
        for (; i < e; ++i) {
            int2 r = ep[i];
            acc = fmaf(__int_as_float(r.y), bf2f(sup[(size_t)r.x * D + d]), acc);
        }
        acc += bias[d];
        if (RELU) acc = fmaxf(acc, 0.f);
        if constexpr (OUT_BF16)
            ((ushort_t*)outv)[(size_t)w * D + d] = f2bf(acc);
        else
            ((float*)outv)[(size_t)w * D + d] = acc;
    }
}

// ---------------------------------------------------------------------------

extern "C" void kernel_launch(void* const* d_in, const int* in_sizes, int n_in,
                              void* d_out, int out_size, void* d_ws, size_t ws_size,
                              hipStream_t stream) {
    const float* x  = (const float*)d_in[0];
    const int*   ei = (const int*)d_in[1];
    const float* ew = (const float*)d_in[2];
    const float* W1 = (const float*)d_in[3];
    const float* b1 = (const float*)d_in[4];
    const float* W2 = (const float*)d_in[5];
    const float* b2 = (const float*)d_in[6];
    float* out = (float*)d_out;

    const int n = in_sizes[0] / IN_DIM;  // 50000
    const int E = in_sizes[2];           // 1600000
    const int* rows = ei;
    const int* cols = ei + E;

    char* ws = (char*)d_ws;
    size_t off = 0;
    auto alloc = [&](size_t bytes) -> void* {
        off = (off + 255) & ~(size_t)255;
        void* p = ws + off;
        off += bytes;
        return p;
    };
    int2*     ep       = (int2*)alloc((size_t)E * sizeof(int2));
    int*      row_ptr  = (int*)alloc((size_t)(n + 1) * sizeof(int));
    int*      bcnt     = (int*)alloc(NBMAX * sizeof(int));
    int*      bbase    = (int*)alloc((NBMAX + 1) * sizeof(int));
    int*      bfill    = (int*)alloc(NBMAX * sizeof(int));
    ushort_t* Wt1      = (ushort_t*)alloc((size_t)IN_DIM * HID_DIM * sizeof(ushort_t));
    ushort_t* Wt2      = (ushort_t*)alloc((size_t)HID_DIM * OUT_DIM * sizeof(ushort_t));
    // sup1 region doubles as ept (bin temp); sized for whichever is larger.
    // sup1: n*128 fp8 = 6.4 MB; sup2 (aliased): n*64 bf16 = 6.4 MB; ept: 12.8 MB.
    size_t sup1_bytes = (size_t)n * HID_DIM * sizeof(unsigned char);
    size_t sup2_bytes = (size_t)n * OUT_DIM * sizeof(ushort_t);
    size_t ept_bytes  = (size_t)E * sizeof(int2);
    size_t reg = sup1_bytes > ept_bytes ? sup1_bytes : ept_bytes;
    if (sup2_bytes > reg) reg = sup2_bytes;
    unsigned char* sup1 = (unsigned char*)alloc(reg);
    ushort_t* h        = (ushort_t*)alloc((size_t)n * HID_DIM * sizeof(ushort_t));
    ushort_t* sup2     = (ushort_t*)sup1;  // sup1 dead after spmm1
    int2*     ept      = (int2*)sup1;      // bin temp aliases sup1 (dead until gemm1)
    // fallback-path scratch (n > 65536)
    int *deg = nullptr, *row_fill = nullptr, *bsum = nullptr, *bscan = nullptr;

    const int nbk = (n + 127) / 128;
    const int gemm_b = (n + 63) / 64;

    // --- weight prep (one merged launch) ---
    k_wcvt2<<<(IN_DIM * HID_DIM + HID_DIM * OUT_DIM + 255) / 256, 256, 0, stream>>>(
        W1, Wt1, W2, Wt2);

    if (n <= 65536) {
        // --- CSR build, bucket-level ---
        hipMemsetAsync(bcnt, 0, NBMAX * sizeof(int), stream);
        k_bhist<<<(E + BH_TILE - 1) / BH_TILE, 256, 0, stream>>>(rows, bcnt, E);
        k_bscan<<<1, 256, 0, stream>>>(bcnt, bbase, bfill, nbk, E);
        k_bin<<<(E + BIN_TILE - 1) / BIN_TILE, 256, 0, stream>>>(rows, cols, ew, bfill, ept, E, nbk);
        k_unbin<<<nbk, 256, 0, stream>>>(bbase, ept, ep, row_ptr, n, E, nbk);
    } else {
        // --- fallback: row-level hist -> scan -> direct scatter ---
        deg      = (int*)alloc((size_t)n * sizeof(int));
        row_fill = (int*)alloc((size_t)n * sizeof(int));
        bsum     = (int*)alloc(256 * sizeof(int));
        bscan    = (int*)alloc(256 * sizeof(int));
        const int nb = (n + SCAN_TILE - 1) / SCAN_TILE;
        k_zero<<<(n + 255) / 256, 256, 0, stream>>>(deg, n);
        k_hist<<<(E + 255) / 256, 256, 0, stream>>>(rows, deg, E);
        k_scan1<<<nb, 256, 0, stream>>>(deg, bsum, n);
        k_scan2<<<1, 256, 0, stream>>>(bsum, bscan, nb);
        k_scan3<<<nb, 256, 0, stream>>>(deg, bscan, row_ptr, row_fill, n, E);
        k_scatter<<<(E + 255) / 256, 256, 0, stream>>>(rows, cols, ew, row_fill, ep, E);
    }

    // --- Layer 1: gemm (fp32->bf16 MFMA, fp8 out) + spmm (fp8 gather, bf16 out)
    k_gemm_mfma<IN_DIM, HID_DIM, false, true><<<gemm_b, 256, 0, stream>>>(x, Wt1, sup1, n);
    k_spmm<HID_DIM, true, true, true><<<(n + 3) / 4, 256, 0, stream>>>(row_ptr, ep, sup1, b1, h, n);

    // --- Layer 2: gemm (bf16 in, bf16 out) + spmm (bf16 gather, fp32 out)
    k_gemm_mfma<HID_DIM, OUT_DIM, true, false><<<gemm_b, 256, 0, stream>>>(h, Wt2, sup2, n);
    k_spmm<OUT_DIM, false, false, false><<<(n + 3) / 4, 256, 0, stream>>>(row_ptr, ep, sup2, b2, out, n);
}